// Round 5
// baseline (461.281 us; speedup 1.0000x reference)
//
#include <hip/hip_runtime.h>
#include <cstdint>
#include <cstddef>

#define NN 100000
#define NE 1000000

typedef unsigned int uint;
typedef unsigned short ushort;
typedef __attribute__((ext_vector_type(8))) short bfrag;   // 8 bf16 = 4 VGPR
typedef __attribute__((ext_vector_type(4))) float f32x4;

__device__ __forceinline__ ushort f2bf(float f){
  uint u = __float_as_uint(f);
  u += 0x7fffu + ((u >> 16) & 1u);     // round-to-nearest-even
  return (ushort)(u >> 16);
}
__device__ __forceinline__ float bflo(uint p){ return __uint_as_float(p << 16); }
__device__ __forceinline__ float bfhi(uint p){ return __uint_as_float(p & 0xffff0000u); }

// ---------------- CSR build ----------------

__global__ __launch_bounds__(256) void k_count(const int* __restrict__ dst, int* __restrict__ cnt){
  int e = blockIdx.x*256 + threadIdx.x;
  if (e < NE) atomicAdd(&cnt[dst[e]], 1);
}

__global__ __launch_bounds__(256) void k_scan_local(const int* __restrict__ cnt, int* __restrict__ rowptr,
                                                    int* __restrict__ bsum){
  __shared__ int sm[256];
  int t = threadIdx.x;
  int i = blockIdx.x*256 + t;
  int v = (i < NN) ? cnt[i] : 0;
  sm[t] = v;
  __syncthreads();
  for (int off=1; off<256; off<<=1){
    int u = (t>=off) ? sm[t-off] : 0;
    __syncthreads();
    sm[t] += u;
    __syncthreads();
  }
  if (i < NN) rowptr[i] = sm[t] - v;
  if (t == 255) bsum[blockIdx.x] = sm[255];
}

__global__ __launch_bounds__(512) void k_scan_bsum(const int* __restrict__ bsum, int* __restrict__ boff, int nb){
  __shared__ int sm[512];
  int t = threadIdx.x;
  int v = (t < nb) ? bsum[t] : 0;
  sm[t] = v;
  __syncthreads();
  for (int off=1; off<512; off<<=1){
    int u = (t>=off) ? sm[t-off] : 0;
    __syncthreads();
    sm[t] += u;
    __syncthreads();
  }
  if (t < nb) boff[t] = sm[t] - v;
}

__global__ __launch_bounds__(256) void k_scan_add(int* __restrict__ rowptr, const int* __restrict__ boff){
  int i = blockIdx.x*256 + threadIdx.x;
  if (i < NN) rowptr[i] += boff[i>>8];
  else if (i == NN) rowptr[NN] = NE;
}

__global__ __launch_bounds__(256) void k_fill(const int* __restrict__ src, const int* __restrict__ dst,
                                              const int* __restrict__ rowptr, int* __restrict__ cnt2,
                                              int* __restrict__ csr, int* __restrict__ epos){
  int e = blockIdx.x*256 + threadIdx.x;
  if (e < NE){
    int d = dst[e];
    int p = atomicAdd(&cnt2[d], 1);
    int slot = rowptr[d] + p;
    csr[slot] = src[e];
    epos[e] = slot;
  }
}

// ---------------- fp32 -> bf16 cast (x) ----------------

__global__ __launch_bounds__(256) void k_cast(const float* __restrict__ x, ushort* __restrict__ xb, int n4){
  int i = blockIdx.x*256 + threadIdx.x;
  if (i < n4){
    float4 v = ((const float4*)x)[i];
    uint2 p;
    p.x = (uint)f2bf(v.x) | ((uint)f2bf(v.y)<<16);
    p.y = (uint)f2bf(v.z) | ((uint)f2bf(v.w)<<16);
    ((uint2*)xb)[i] = p;
  }
}

// ---------------- weight -> B-fragment pack ----------------

__global__ __launch_bounds__(256) void k_bfrag(const float* __restrict__ B1, const float* __restrict__ B2,
                                               int n1, int n2, int NT, ushort* __restrict__ out){
  int i = blockIdx.x*256 + threadIdx.x;
  if (i >= NT*4*64) return;
  int l = i & 63, ks = (i>>6)&3, nt = i>>8;
  int col = nt*16 + (l&15);
  int k0  = ks*32 + (l>>4)*8;
  const float* B; int stride, c;
  if (col < n1){ B = B1; stride = n1; c = col; }
  else         { B = B2; stride = n2; c = col - n1; }
  ushort v[8];
  #pragma unroll
  for (int j=0;j<8;j++) v[j] = f2bf(B[(size_t)(k0+j)*stride + c]);
  uint4 pk;
  pk.x = (uint)v[0] | ((uint)v[1]<<16);
  pk.y = (uint)v[2] | ((uint)v[3]<<16);
  pk.z = (uint)v[4] | ((uint)v[5]<<16);
  pk.w = (uint)v[6] | ((uint)v[7]<<16);
  *(uint4*)(out + (size_t)i*8) = pk;
}

// ---------------- MFMA GEMM, K=128, no LDS ----------------

template<int NT, int NTF, int H>
__global__ __launch_bounds__(256) void k_gemm_mfma(const ushort* __restrict__ Ab, const ushort* __restrict__ Bf,
                                                   ushort* __restrict__ featb, float* __restrict__ Cres,
                                                   const float* __restrict__ al, const float* __restrict__ ar,
                                                   float* __restrict__ el, float* __restrict__ er, int M){
  int t = threadIdx.x;
  int l = t & 63, w = t >> 6;
  int rw = blockIdx.x*64 + w*16;
  int c = l & 15, g = l >> 4;

  f32x4 acc[NT];
  #pragma unroll
  for (int nt=0;nt<NT;nt++) acc[nt] = (f32x4){0.f,0.f,0.f,0.f};

  int rowA = rw + c; if (rowA >= M) rowA = M-1;
  const ushort* Ap = Ab + (size_t)rowA*128 + g*8;
  const bfrag* Bp = (const bfrag*)Bf;

  #pragma unroll
  for (int ks=0; ks<4; ++ks){
    bfrag a = *(const bfrag*)(Ap + ks*32);
    #pragma unroll
    for (int nt=0; nt<NT; ++nt){
      bfrag b = Bp[(nt*4+ks)*64 + l];
      acc[nt] = __builtin_amdgcn_mfma_f32_16x16x32_bf16(a, b, acc[nt], 0, 0, 0);
    }
  }

  float alv[H][2], arv[H][2];
  #pragma unroll
  for (int h=0;h<H;h++){
    alv[h][0]=al[h*32+c];    arv[h][0]=ar[h*32+c];
    alv[h][1]=al[h*32+16+c]; arv[h][1]=ar[h*32+16+c];
  }

  #pragma unroll
  for (int reg=0; reg<4; ++reg){
    int row = rw + g*4 + reg;
    bool ok = row < M;
    #pragma unroll
    for (int h=0;h<H;h++){
      float pl = acc[2*h][reg]*alv[h][0] + acc[2*h+1][reg]*alv[h][1];
      float pr = acc[2*h][reg]*arv[h][0] + acc[2*h+1][reg]*arv[h][1];
      #pragma unroll
      for (int off=1; off<16; off<<=1){ pl += __shfl_xor(pl,off); pr += __shfl_xor(pr,off); }
      if (ok && c==0){ el[(size_t)row*H + h] = pl; er[(size_t)row*H + h] = pr; }
    }
    if (ok){
      #pragma unroll
      for (int nt=0; nt<NTF; ++nt)
        featb[(size_t)row*(NTF*16) + nt*16 + c] = f2bf(acc[nt][reg]);
      #pragma unroll
      for (int nt=NTF; nt<NT; ++nt)
        Cres[(size_t)row*((NT-NTF)*16) + (nt-NTF)*16 + c] = acc[nt][reg];
    }
  }
}

// ---------------- edge numerators, scattered to CSR order ----------------
// ex[epos[e]*H + h] = exp(leaky(el[src]+er[dst]))

template<int H>
__global__ __launch_bounds__(256) void k_edge(const int* __restrict__ src, const int* __restrict__ dst,
                                              const int* __restrict__ epos,
                                              const float* __restrict__ el, const float* __restrict__ er,
                                              float* __restrict__ ex){
  int e = blockIdx.x*256 + threadIdx.x;
  if (e >= NE) return;
  int s = src[e], d = dst[e], p = epos[e];
  if (H == 4){
    float4 elv = *(const float4*)(el + (size_t)s*4);
    float4 erv = *(const float4*)(er + (size_t)d*4);
    float4 o;
    float v0 = elv.x + erv.x; v0 = (v0>0.f)?v0:0.2f*v0; o.x = __expf(v0);
    float v1 = elv.y + erv.y; v1 = (v1>0.f)?v1:0.2f*v1; o.y = __expf(v1);
    float v2 = elv.z + erv.z; v2 = (v2>0.f)?v2:0.2f*v2; o.z = __expf(v2);
    float v3 = elv.w + erv.w; v3 = (v3>0.f)?v3:0.2f*v3; o.w = __expf(v3);
    *(float4*)(ex + (size_t)p*4) = o;
  } else {
    float v = el[s] + er[d];
    v = (v>0.f)?v:0.2f*v;
    ex[p] = __expf(v);
  }
}

// ---------------- aggregation: one wave per dst node ----------------
// ex is CSR-ordered softmax numerators. RK: 0=none 1=bf16 2=fp32 residual.

template<int H, int RK, bool OBF>
__global__ __launch_bounds__(256) void k_agg(const int* __restrict__ rowptr, const int* __restrict__ csr,
                                             const ushort* __restrict__ feat, const float* __restrict__ ex,
                                             const void* __restrict__ res, const float* __restrict__ bias,
                                             void* __restrict__ out, int act){
  int lane = threadIdx.x & 63;
  int node = blockIdx.x*4 + (threadIdx.x >> 6);

  int beg = rowptr[node], end = rowptr[node+1];
  int deg = end - beg;

  const ushort* resb = (const ushort*)res;
  const float*  resf = (const float*)res;

  // ---- pass 1: per-head sums of ex (coalesced streaming) ----
  float ssum = 0.f;
  if (H == 4){
    const float* exb = ex + (size_t)beg*4;
    for (int idx = lane; idx < deg*4; idx += 64) ssum += exb[idx];
    #pragma unroll
    for (int off=4; off<64; off<<=1) ssum += __shfl_xor(ssum, off);
  } else {
    const float* exb = ex + beg;
    for (int idx = lane; idx < deg; idx += 64) ssum += exb[idx];
    #pragma unroll
    for (int off=1; off<64; off<<=1) ssum += __shfl_xor(ssum, off);
  }

  // ---- pass 2: gather-accumulate ----
  if (H == 4){
    int g = lane >> 4;
    float sg = __shfl(ssum, g);          // lane g (g<4) holds head-g sum
    float inv = (deg > 0) ? 1.f/sg : 0.f;
    const float* exg = ex + (size_t)beg*4 + g;
    const int* cp = csr + beg;
    float a0 = 0.f, a1 = 0.f;

    int ei = 0;
    for (; ei+4 <= deg; ei += 4){
      int s0 = cp[ei], s1 = cp[ei+1], s2 = cp[ei+2], s3 = cp[ei+3];
      uint p0 = *(const uint*)(feat + (size_t)s0*128 + 2*lane);
      uint p1 = *(const uint*)(feat + (size_t)s1*128 + 2*lane);
      uint p2 = *(const uint*)(feat + (size_t)s2*128 + 2*lane);
      uint p3 = *(const uint*)(feat + (size_t)s3*128 + 2*lane);
      float w0 = exg[4*ei]    * inv;
      float w1 = exg[4*ei+4]  * inv;
      float w2 = exg[4*ei+8]  * inv;
      float w3 = exg[4*ei+12] * inv;
      a0 += w0*bflo(p0) + w1*bflo(p1) + w2*bflo(p2) + w3*bflo(p3);
      a1 += w0*bfhi(p0) + w1*bfhi(p1) + w2*bfhi(p2) + w3*bfhi(p3);
    }
    for (; ei < deg; ++ei){
      int s0 = cp[ei];
      uint p0 = *(const uint*)(feat + (size_t)s0*128 + 2*lane);
      float w0 = exg[4*ei] * inv;
      a0 += w0*bflo(p0);
      a1 += w0*bfhi(p0);
    }

    float o0 = a0, o1 = a1;
    if (RK == 1){
      uint rv = *(const uint*)(resb + (size_t)node*128 + 2*lane);
      o0 += bflo(rv); o1 += bfhi(rv);
    } else if (RK == 2){
      float2 rv = *(const float2*)(resf + (size_t)node*128 + 2*lane);
      o0 += rv.x; o1 += rv.y;
    }
    o0 += bias[2*lane]; o1 += bias[2*lane+1];
    if (act){
      o0 = (o0>0.f) ? o0 : __expf(o0)-1.f;
      o1 = (o1>0.f) ? o1 : __expf(o1)-1.f;
    }
    if (OBF){
      uint pk = (uint)f2bf(o0) | ((uint)f2bf(o1)<<16);
      *(uint*)((ushort*)out + (size_t)node*128 + 2*lane) = pk;
    } else {
      float2 ov; ov.x = o0; ov.y = o1;
      *(float2*)((float*)out + (size_t)node*128 + 2*lane) = ov;
    }
  } else {
    float s0v = __shfl(ssum, 0);
    float inv = (deg > 0) ? 1.f/s0v : 0.f;
    int sub = lane >> 4;
    int fl  = lane & 15;
    const int* cp = csr + beg;
    const float* exb = ex + beg;
    float a0 = 0.f, a1 = 0.f;
    for (int ei = sub; ei < deg; ei += 4){
      int s = cp[ei];
      uint pv = *(const uint*)(feat + (size_t)s*32 + 2*fl);
      float w = exb[ei] * inv;
      a0 += w*bflo(pv);
      a1 += w*bfhi(pv);
    }
    a0 += __shfl_xor(a0,16); a0 += __shfl_xor(a0,32);
    a1 += __shfl_xor(a1,16); a1 += __shfl_xor(a1,32);
    if (lane < 16){
      float o0 = a0, o1 = a1;
      if (RK == 1){
        uint rv = *(const uint*)(resb + (size_t)node*32 + 2*fl);
        o0 += bflo(rv); o1 += bfhi(rv);
      } else if (RK == 2){
        float2 rv = *(const float2*)(resf + (size_t)node*32 + 2*fl);
        o0 += rv.x; o1 += rv.y;
      }
      o0 += bias[2*fl]; o1 += bias[2*fl+1];
      if (act){
        o0 = (o0>0.f) ? o0 : __expf(o0)-1.f;
        o1 = (o1>0.f) ? o1 : __expf(o1)-1.f;
      }
      if (OBF){
        uint pk = (uint)f2bf(o0) | ((uint)f2bf(o1)<<16);
        *(uint*)((ushort*)out + (size_t)node*32 + 2*fl) = pk;
      } else {
        float2 ov; ov.x = o0; ov.y = o1;
        *(float2*)((float*)out + (size_t)node*32 + 2*fl) = ov;
      }
    }
  }
}

// ---------------- final FC: out[N,40] = h[N,32] @ Wfc[32,40] + bfc ----------------

__global__ __launch_bounds__(256) void k_fc(const float* __restrict__ h, const float* __restrict__ W,
                                            const float* __restrict__ b, float* __restrict__ out){
  __shared__ float Ws[32*40];
  __shared__ float Hs[64][33];
  __shared__ float bs[40];
  int t = threadIdx.x;
  for (int i=t; i<1280; i+=256) Ws[i] = W[i];
  if (t < 40) bs[t] = b[t];
  int n0 = blockIdx.x*64;
  for (int idx=t; idx<512; idx+=256){
    int r = idx>>3, c4 = idx&7;
    float4 v;
    if (n0 + r < NN) v = *(const float4*)(h + (size_t)(n0+r)*32 + c4*4);
    else v = make_float4(0.f,0.f,0.f,0.f);
    Hs[r][c4*4+0]=v.x; Hs[r][c4*4+1]=v.y; Hs[r][c4*4+2]=v.z; Hs[r][c4*4+3]=v.w;
  }
  __syncthreads();
  int n = t>>2, cg = t&3;
  float acc[10];
  #pragma unroll
  for (int j=0;j<10;j++) acc[j] = 0.f;
  #pragma unroll
  for (int k=0;k<32;k++){
    float hv = Hs[n][k];
    #pragma unroll
    for (int j=0;j<10;j++) acc[j] += hv * Ws[k*40 + cg + 4*j];
  }
  int row = n0 + n;
  if (row < NN){
    #pragma unroll
    for (int j=0;j<10;j++) out[(size_t)row*40 + cg + 4*j] = acc[j] + bs[cg+4*j];
  }
}

// ---------------- launch ----------------

extern "C" void kernel_launch(void* const* d_in, const int* in_sizes, int n_in,
                              void* d_out, int out_size, void* d_ws, size_t ws_size,
                              hipStream_t stream){
  const float* x    = (const float*)d_in[0];
  const int*   src  = (const int*)  d_in[1];
  const int*   dst  = (const int*)  d_in[2];
  const float* W1   = (const float*)d_in[3];
  const float* al1  = (const float*)d_in[4];
  const float* ar1  = (const float*)d_in[5];
  const float* b1   = (const float*)d_in[6];
  const float* W2   = (const float*)d_in[7];
  const float* al2  = (const float*)d_in[8];
  const float* ar2  = (const float*)d_in[9];
  const float* b2   = (const float*)d_in[10];
  const float* W3   = (const float*)d_in[11];
  const float* al3  = (const float*)d_in[12];
  const float* ar3  = (const float*)d_in[13];
  const float* b3   = (const float*)d_in[14];
  const float* res3 = (const float*)d_in[15];
  const float* Wfc  = (const float*)d_in[16];
  const float* bfc  = (const float*)d_in[17];
  float* out = (float*)d_out;

  char* ws = (char*)d_ws;
  size_t o = 0;
  auto alloc = [&](size_t bytes)->char*{
    char* p = ws + o;
    o += (bytes + 255) & ~(size_t)255;
    return p;
  };
  int*    rowptr = (int*)   alloc((size_t)(NN+1)*4);
  int*    cnt    = (int*)   alloc((size_t)NN*4);
  int*    cnt2   = (int*)   alloc((size_t)NN*4);
  int*    bsum   = (int*)   alloc(512*4);
  int*    boff   = (int*)   alloc(512*4);
  int*    csr    = (int*)   alloc((size_t)NE*4);
  int*    epos   = (int*)   alloc((size_t)NE*4);
  float*  el     = (float*) alloc((size_t)NN*4*4);
  float*  er     = (float*) alloc((size_t)NN*4*4);
  float*  ex     = (float*) alloc((size_t)NE*4*4);     // CSR-ordered softmax numerators
  ushort* xb     = (ushort*)alloc((size_t)NN*128*2);
  ushort* featb  = (ushort*)alloc((size_t)NN*128*2);
  ushort* h1b    = (ushort*)alloc((size_t)NN*128*2);
  ushort* h2b    = (ushort*)alloc((size_t)NN*128*2);
  float*  res3p  = (float*) alloc((size_t)NN*32*4);
  float*  h3     = (float*) alloc((size_t)NN*32*4);
  ushort* Bf1    = (ushort*)alloc((size_t)8*4*64*8*2);
  ushort* Bf2    = (ushort*)alloc((size_t)8*4*64*8*2);
  ushort* Bf3    = (ushort*)alloc((size_t)4*4*64*8*2);
  (void)ws_size; (void)n_in; (void)in_sizes; (void)out_size;

  // CSR build (graph identical across layers)
  hipMemsetAsync(cnt,  0, (size_t)NN*4, stream);
  hipMemsetAsync(cnt2, 0, (size_t)NN*4, stream);
  k_count<<<(NE+255)/256, 256, 0, stream>>>(dst, cnt);
  int nb = (NN+255)/256;
  k_scan_local<<<nb, 256, 0, stream>>>(cnt, rowptr, bsum);
  k_scan_bsum<<<1, 512, 0, stream>>>(bsum, boff, nb);
  k_scan_add<<<(NN+1+255)/256, 256, 0, stream>>>(rowptr, boff);
  k_fill<<<(NE+255)/256, 256, 0, stream>>>(src, dst, rowptr, cnt2, csr, epos);

  // pre-casts / weight packs
  k_cast<<<(NN*128/4+255)/256, 256, 0, stream>>>(x, xb, NN*128/4);
  k_bfrag<<<8, 256, 0, stream>>>(W1, nullptr, 128, 0, 8, Bf1);
  k_bfrag<<<8, 256, 0, stream>>>(W2, nullptr, 128, 0, 8, Bf2);
  k_bfrag<<<4, 256, 0, stream>>>(W3, res3, 32, 32, 4, Bf3);

  int gemm_blocks = (NN+63)/64;

  // ---- Layer 1: 128 -> 4x32, no residual, ELU ----
  k_gemm_mfma<8,8,4><<<gemm_blocks, 256, 0, stream>>>(xb, Bf1, featb, nullptr, al1, ar1, el, er, NN);
  k_edge<4><<<(NE+255)/256, 256, 0, stream>>>(src, dst, epos, el, er, ex);
  k_agg<4,0,true><<<NN/4, 256, 0, stream>>>(rowptr, csr, featb, ex, nullptr, b1, h1b, 1);

  // ---- Layer 2: 128 -> 4x32, identity residual, ELU ----
  k_gemm_mfma<8,8,4><<<gemm_blocks, 256, 0, stream>>>(h1b, Bf2, featb, nullptr, al2, ar2, el, er, NN);
  k_edge<4><<<(NE+255)/256, 256, 0, stream>>>(src, dst, epos, el, er, ex);
  k_agg<4,1,true><<<NN/4, 256, 0, stream>>>(rowptr, csr, featb, ex, h1b, b2, h2b, 1);

  // ---- Layer 3: fused feat3 + projected residual, 1 head, no act ----
  k_gemm_mfma<4,2,1><<<gemm_blocks, 256, 0, stream>>>(h2b, Bf3, featb, res3p, al3, ar3, el, er, NN);
  k_edge<1><<<(NE+255)/256, 256, 0, stream>>>(src, dst, epos, el, er, ex);
  k_agg<1,2,false><<<NN/4, 256, 0, stream>>>(rowptr, csr, featb, ex, res3p, b3, h3, 0);

  // ---- classifier ----
  k_fc<<<gemm_blocks, 256, 0, stream>>>(h3, Wfc, bfc, out);
}

// Round 6
// 373.778 us; speedup vs baseline: 1.2341x; 1.2341x over previous
//
#include <hip/hip_runtime.h>
#include <cstdint>
#include <cstddef>

#define NN 100000
#define NE 1000000

typedef unsigned int uint;
typedef unsigned short ushort;
typedef __attribute__((ext_vector_type(8))) short bfrag;   // 8 bf16 = 4 VGPR
typedef __attribute__((ext_vector_type(4))) float f32x4;

__device__ __forceinline__ ushort f2bf(float f){
  uint u = __float_as_uint(f);
  u += 0x7fffu + ((u >> 16) & 1u);     // round-to-nearest-even
  return (ushort)(u >> 16);
}
__device__ __forceinline__ float bflo(uint p){ return __uint_as_float(p << 16); }
__device__ __forceinline__ float bfhi(uint p){ return __uint_as_float(p & 0xffff0000u); }

// ---------------- CSR build ----------------
// pass 1: histogram + ticket in ONE atomic pass
__global__ __launch_bounds__(256) void k_ticket(const int* __restrict__ dst, int* __restrict__ cnt,
                                                int* __restrict__ tick){
  int e = blockIdx.x*256 + threadIdx.x;
  if (e < NE) tick[e] = atomicAdd(&cnt[dst[e]], 1);
}

__global__ __launch_bounds__(256) void k_scan_local(const int* __restrict__ cnt, int* __restrict__ rowptr,
                                                    int* __restrict__ bsum){
  __shared__ int sm[256];
  int t = threadIdx.x;
  int i = blockIdx.x*256 + t;
  int v = (i < NN) ? cnt[i] : 0;
  sm[t] = v;
  __syncthreads();
  for (int off=1; off<256; off<<=1){
    int u = (t>=off) ? sm[t-off] : 0;
    __syncthreads();
    sm[t] += u;
    __syncthreads();
  }
  if (i < NN) rowptr[i] = sm[t] - v;
  if (t == 255) bsum[blockIdx.x] = sm[255];
}

__global__ __launch_bounds__(512) void k_scan_bsum(const int* __restrict__ bsum, int* __restrict__ boff, int nb){
  __shared__ int sm[512];
  int t = threadIdx.x;
  int v = (t < nb) ? bsum[t] : 0;
  sm[t] = v;
  __syncthreads();
  for (int off=1; off<512; off<<=1){
    int u = (t>=off) ? sm[t-off] : 0;
    __syncthreads();
    sm[t] += u;
    __syncthreads();
  }
  if (t < nb) boff[t] = sm[t] - v;
}

__global__ __launch_bounds__(256) void k_scan_add(int* __restrict__ rowptr, const int* __restrict__ boff){
  int i = blockIdx.x*256 + threadIdx.x;
  if (i < NN) rowptr[i] += boff[i>>8];
  else if (i == NN) rowptr[NN] = NE;
}

// pass 2: atomic-free placement; csr2[slot] = (src, dst)
__global__ __launch_bounds__(256) void k_place(const int* __restrict__ src, const int* __restrict__ dst,
                                               const int* __restrict__ rowptr, const int* __restrict__ tick,
                                               int2* __restrict__ csr2){
  int e = blockIdx.x*256 + threadIdx.x;
  if (e < NE){
    int d = dst[e];
    int slot = rowptr[d] + tick[e];
    csr2[slot] = make_int2(src[e], d);
  }
}

// ---------------- fused prep: x->bf16 cast + 3 weight-fragment packs ----------------

__device__ __forceinline__ void bfrag_body(const float* __restrict__ B1, const float* __restrict__ B2,
                                           int n1, int n2, int NT, ushort* __restrict__ out, int i){
  if (i >= NT*4*64) return;
  int l = i & 63, ks = (i>>6)&3, nt = i>>8;
  int col = nt*16 + (l&15);
  int k0  = ks*32 + (l>>4)*8;
  const float* B; int stride, c;
  if (col < n1){ B = B1; stride = n1; c = col; }
  else         { B = B2; stride = n2; c = col - n1; }
  ushort v[8];
  #pragma unroll
  for (int j=0;j<8;j++) v[j] = f2bf(B[(size_t)(k0+j)*stride + c]);
  uint4 pk;
  pk.x = (uint)v[0] | ((uint)v[1]<<16);
  pk.y = (uint)v[2] | ((uint)v[3]<<16);
  pk.z = (uint)v[4] | ((uint)v[5]<<16);
  pk.w = (uint)v[6] | ((uint)v[7]<<16);
  *(uint4*)(out + (size_t)i*8) = pk;
}

#define CAST_BLOCKS 12500   // NN*128/4 / 256

__global__ __launch_bounds__(256) void k_prep(const float* __restrict__ x, ushort* __restrict__ xb,
                                              const float* __restrict__ W1, const float* __restrict__ W2,
                                              const float* __restrict__ W3, const float* __restrict__ res3,
                                              ushort* __restrict__ Bf1, ushort* __restrict__ Bf2,
                                              ushort* __restrict__ Bf3){
  int bid = blockIdx.x, t = threadIdx.x;
  if (bid < CAST_BLOCKS){
    int i = bid*256 + t;                      // < 3.2M exactly
    float4 v = ((const float4*)x)[i];
    uint2 p;
    p.x = (uint)f2bf(v.x) | ((uint)f2bf(v.y)<<16);
    p.y = (uint)f2bf(v.z) | ((uint)f2bf(v.w)<<16);
    ((uint2*)xb)[i] = p;
  } else {
    int r = bid - CAST_BLOCKS;                // 0..19
    if (r < 8)       bfrag_body(W1, nullptr, 128, 0, 8, Bf1, r*256 + t);
    else if (r < 16) bfrag_body(W2, nullptr, 128, 0, 8, Bf2, (r-8)*256 + t);
    else             bfrag_body(W3, res3,    32, 32, 4, Bf3, (r-16)*256 + t);
  }
}

// ---------------- MFMA GEMM, K=128, no LDS ----------------

template<int NT, int NTF, int H>
__global__ __launch_bounds__(256) void k_gemm_mfma(const ushort* __restrict__ Ab, const ushort* __restrict__ Bf,
                                                   ushort* __restrict__ featb, float* __restrict__ Cres,
                                                   const float* __restrict__ al, const float* __restrict__ ar,
                                                   float* __restrict__ el, float* __restrict__ er, int M){
  int t = threadIdx.x;
  int l = t & 63, w = t >> 6;
  int rw = blockIdx.x*64 + w*16;
  int c = l & 15, g = l >> 4;

  f32x4 acc[NT];
  #pragma unroll
  for (int nt=0;nt<NT;nt++) acc[nt] = (f32x4){0.f,0.f,0.f,0.f};

  int rowA = rw + c; if (rowA >= M) rowA = M-1;
  const ushort* Ap = Ab + (size_t)rowA*128 + g*8;
  const bfrag* Bp = (const bfrag*)Bf;

  #pragma unroll
  for (int ks=0; ks<4; ++ks){
    bfrag a = *(const bfrag*)(Ap + ks*32);
    #pragma unroll
    for (int nt=0; nt<NT; ++nt){
      bfrag b = Bp[(nt*4+ks)*64 + l];
      acc[nt] = __builtin_amdgcn_mfma_f32_16x16x32_bf16(a, b, acc[nt], 0, 0, 0);
    }
  }

  float alv[H][2], arv[H][2];
  #pragma unroll
  for (int h=0;h<H;h++){
    alv[h][0]=al[h*32+c];    arv[h][0]=ar[h*32+c];
    alv[h][1]=al[h*32+16+c]; arv[h][1]=ar[h*32+16+c];
  }

  #pragma unroll
  for (int reg=0; reg<4; ++reg){
    int row = rw + g*4 + reg;
    bool ok = row < M;
    #pragma unroll
    for (int h=0;h<H;h++){
      float pl = acc[2*h][reg]*alv[h][0] + acc[2*h+1][reg]*alv[h][1];
      float pr = acc[2*h][reg]*arv[h][0] + acc[2*h+1][reg]*arv[h][1];
      #pragma unroll
      for (int off=1; off<16; off<<=1){ pl += __shfl_xor(pl,off); pr += __shfl_xor(pr,off); }
      if (ok && c==0){ el[(size_t)row*H + h] = pl; er[(size_t)row*H + h] = pr; }
    }
    if (ok){
      #pragma unroll
      for (int nt=0; nt<NTF; ++nt)
        featb[(size_t)row*(NTF*16) + nt*16 + c] = f2bf(acc[nt][reg]);
      #pragma unroll
      for (int nt=NTF; nt<NT; ++nt)
        Cres[(size_t)row*((NT-NTF)*16) + (nt-NTF)*16 + c] = acc[nt][reg];
    }
  }
}

// ---------------- edge numerators, slot-parallel (fully coalesced I/O) ----------------

template<int H>
__global__ __launch_bounds__(256) void k_edge(const int2* __restrict__ csr2,
                                              const float* __restrict__ el, const float* __restrict__ er,
                                              float* __restrict__ ex){
  int slot = blockIdx.x*256 + threadIdx.x;
  if (slot >= NE) return;
  int2 sd = csr2[slot];
  if (H == 4){
    float4 elv = *(const float4*)(el + (size_t)sd.x*4);
    float4 erv = *(const float4*)(er + (size_t)sd.y*4);
    float4 o;
    float v0 = elv.x + erv.x; v0 = (v0>0.f)?v0:0.2f*v0; o.x = __expf(v0);
    float v1 = elv.y + erv.y; v1 = (v1>0.f)?v1:0.2f*v1; o.y = __expf(v1);
    float v2 = elv.z + erv.z; v2 = (v2>0.f)?v2:0.2f*v2; o.z = __expf(v2);
    float v3 = elv.w + erv.w; v3 = (v3>0.f)?v3:0.2f*v3; o.w = __expf(v3);
    *(float4*)(ex + (size_t)slot*4) = o;
  } else {
    float v = el[sd.x] + er[sd.y];
    v = (v>0.f)?v:0.2f*v;
    ex[slot] = __expf(v);
  }
}

// ---------------- aggregation: one wave per dst node ----------------
// ex is CSR-slot-ordered softmax numerators. RK: 0=none 1=bf16 2=fp32 residual.

template<int H, int RK, bool OBF>
__global__ __launch_bounds__(256) void k_agg(const int* __restrict__ rowptr, const int2* __restrict__ csr2,
                                             const ushort* __restrict__ feat, const float* __restrict__ ex,
                                             const void* __restrict__ res, const float* __restrict__ bias,
                                             void* __restrict__ out, int act){
  int lane = threadIdx.x & 63;
  int node = blockIdx.x*4 + (threadIdx.x >> 6);

  int beg = rowptr[node], end = rowptr[node+1];
  int deg = end - beg;

  const ushort* resb = (const ushort*)res;
  const float*  resf = (const float*)res;

  // ---- pass 1: per-head sums of ex (coalesced streaming) ----
  float ssum = 0.f;
  if (H == 4){
    const float* exb = ex + (size_t)beg*4;
    for (int idx = lane; idx < deg*4; idx += 64) ssum += exb[idx];
    #pragma unroll
    for (int off=4; off<64; off<<=1) ssum += __shfl_xor(ssum, off);
  } else {
    const float* exb = ex + beg;
    for (int idx = lane; idx < deg; idx += 64) ssum += exb[idx];
    #pragma unroll
    for (int off=1; off<64; off<<=1) ssum += __shfl_xor(ssum, off);
  }

  // ---- pass 2: gather-accumulate ----
  if (H == 4){
    int g = lane >> 4;
    float sg = __shfl(ssum, g);          // lane g (g<4) holds head-g sum
    float inv = (deg > 0) ? 1.f/sg : 0.f;
    const float* exg = ex + (size_t)beg*4 + g;
    const int2* cp = csr2 + beg;
    float a0 = 0.f, a1 = 0.f;

    int ei = 0;
    for (; ei+8 <= deg; ei += 8){
      int s0 = cp[ei].x,   s1 = cp[ei+1].x, s2 = cp[ei+2].x, s3 = cp[ei+3].x;
      int s4 = cp[ei+4].x, s5 = cp[ei+5].x, s6 = cp[ei+6].x, s7 = cp[ei+7].x;
      uint p0 = *(const uint*)(feat + (size_t)s0*128 + 2*lane);
      uint p1 = *(const uint*)(feat + (size_t)s1*128 + 2*lane);
      uint p2 = *(const uint*)(feat + (size_t)s2*128 + 2*lane);
      uint p3 = *(const uint*)(feat + (size_t)s3*128 + 2*lane);
      uint p4 = *(const uint*)(feat + (size_t)s4*128 + 2*lane);
      uint p5 = *(const uint*)(feat + (size_t)s5*128 + 2*lane);
      uint p6 = *(const uint*)(feat + (size_t)s6*128 + 2*lane);
      uint p7 = *(const uint*)(feat + (size_t)s7*128 + 2*lane);
      float w0 = exg[4*ei]    * inv, w1 = exg[4*ei+4]  * inv;
      float w2 = exg[4*ei+8]  * inv, w3 = exg[4*ei+12] * inv;
      float w4 = exg[4*ei+16] * inv, w5 = exg[4*ei+20] * inv;
      float w6 = exg[4*ei+24] * inv, w7 = exg[4*ei+28] * inv;
      a0 += w0*bflo(p0) + w1*bflo(p1) + w2*bflo(p2) + w3*bflo(p3)
          + w4*bflo(p4) + w5*bflo(p5) + w6*bflo(p6) + w7*bflo(p7);
      a1 += w0*bfhi(p0) + w1*bfhi(p1) + w2*bfhi(p2) + w3*bfhi(p3)
          + w4*bfhi(p4) + w5*bfhi(p5) + w6*bfhi(p6) + w7*bfhi(p7);
    }
    for (; ei < deg; ++ei){
      int s0 = cp[ei].x;
      uint p0 = *(const uint*)(feat + (size_t)s0*128 + 2*lane);
      float w0 = exg[4*ei] * inv;
      a0 += w0*bflo(p0);
      a1 += w0*bfhi(p0);
    }

    float o0 = a0, o1 = a1;
    if (RK == 1){
      uint rv = *(const uint*)(resb + (size_t)node*128 + 2*lane);
      o0 += bflo(rv); o1 += bfhi(rv);
    } else if (RK == 2){
      float2 rv = *(const float2*)(resf + (size_t)node*128 + 2*lane);
      o0 += rv.x; o1 += rv.y;
    }
    o0 += bias[2*lane]; o1 += bias[2*lane+1];
    if (act){
      o0 = (o0>0.f) ? o0 : __expf(o0)-1.f;
      o1 = (o1>0.f) ? o1 : __expf(o1)-1.f;
    }
    if (OBF){
      uint pk = (uint)f2bf(o0) | ((uint)f2bf(o1)<<16);
      *(uint*)((ushort*)out + (size_t)node*128 + 2*lane) = pk;
    } else {
      float2 ov; ov.x = o0; ov.y = o1;
      *(float2*)((float*)out + (size_t)node*128 + 2*lane) = ov;
    }
  } else {
    float s0v = __shfl(ssum, 0);
    float inv = (deg > 0) ? 1.f/s0v : 0.f;
    int sub = lane >> 4;
    int fl  = lane & 15;
    const int2* cp = csr2 + beg;
    const float* exb = ex + beg;
    float a0 = 0.f, a1 = 0.f;
    for (int ei = sub; ei < deg; ei += 4){
      int s = cp[ei].x;
      uint pv = *(const uint*)(feat + (size_t)s*32 + 2*fl);
      float w = exb[ei] * inv;
      a0 += w*bflo(pv);
      a1 += w*bfhi(pv);
    }
    a0 += __shfl_xor(a0,16); a0 += __shfl_xor(a0,32);
    a1 += __shfl_xor(a1,16); a1 += __shfl_xor(a1,32);
    if (lane < 16){
      float o0 = a0, o1 = a1;
      if (RK == 1){
        uint rv = *(const uint*)(resb + (size_t)node*32 + 2*fl);
        o0 += bflo(rv); o1 += bfhi(rv);
      } else if (RK == 2){
        float2 rv = *(const float2*)(resf + (size_t)node*32 + 2*fl);
        o0 += rv.x; o1 += rv.y;
      }
      o0 += bias[2*fl]; o1 += bias[2*fl+1];
      if (act){
        o0 = (o0>0.f) ? o0 : __expf(o0)-1.f;
        o1 = (o1>0.f) ? o1 : __expf(o1)-1.f;
      }
      if (OBF){
        uint pk = (uint)f2bf(o0) | ((uint)f2bf(o1)<<16);
        *(uint*)((ushort*)out + (size_t)node*32 + 2*fl) = pk;
      } else {
        float2 ov; ov.x = o0; ov.y = o1;
        *(float2*)((float*)out + (size_t)node*32 + 2*fl) = ov;
      }
    }
  }
}

// ---------------- final FC: out[N,40] = h[N,32] @ Wfc[32,40] + bfc ----------------

__global__ __launch_bounds__(256) void k_fc(const float* __restrict__ h, const float* __restrict__ W,
                                            const float* __restrict__ b, float* __restrict__ out){
  __shared__ float Ws[32*40];
  __shared__ float Hs[64][33];
  __shared__ float bs[40];
  int t = threadIdx.x;
  for (int i=t; i<1280; i+=256) Ws[i] = W[i];
  if (t < 40) bs[t] = b[t];
  int n0 = blockIdx.x*64;
  for (int idx=t; idx<512; idx+=256){
    int r = idx>>3, c4 = idx&7;
    float4 v;
    if (n0 + r < NN) v = *(const float4*)(h + (size_t)(n0+r)*32 + c4*4);
    else v = make_float4(0.f,0.f,0.f,0.f);
    Hs[r][c4*4+0]=v.x; Hs[r][c4*4+1]=v.y; Hs[r][c4*4+2]=v.z; Hs[r][c4*4+3]=v.w;
  }
  __syncthreads();
  int n = t>>2, cg = t&3;
  float acc[10];
  #pragma unroll
  for (int j=0;j<10;j++) acc[j] = 0.f;
  #pragma unroll
  for (int k=0;k<32;k++){
    float hv = Hs[n][k];
    #pragma unroll
    for (int j=0;j<10;j++) acc[j] += hv * Ws[k*40 + cg + 4*j];
  }
  int row = n0 + n;
  if (row < NN){
    #pragma unroll
    for (int j=0;j<10;j++) out[(size_t)row*40 + cg + 4*j] = acc[j] + bs[cg+4*j];
  }
}

// ---------------- launch ----------------

extern "C" void kernel_launch(void* const* d_in, const int* in_sizes, int n_in,
                              void* d_out, int out_size, void* d_ws, size_t ws_size,
                              hipStream_t stream){
  const float* x    = (const float*)d_in[0];
  const int*   src  = (const int*)  d_in[1];
  const int*   dst  = (const int*)  d_in[2];
  const float* W1   = (const float*)d_in[3];
  const float* al1  = (const float*)d_in[4];
  const float* ar1  = (const float*)d_in[5];
  const float* b1   = (const float*)d_in[6];
  const float* W2   = (const float*)d_in[7];
  const float* al2  = (const float*)d_in[8];
  const float* ar2  = (const float*)d_in[9];
  const float* b2   = (const float*)d_in[10];
  const float* W3   = (const float*)d_in[11];
  const float* al3  = (const float*)d_in[12];
  const float* ar3  = (const float*)d_in[13];
  const float* b3   = (const float*)d_in[14];
  const float* res3 = (const float*)d_in[15];
  const float* Wfc  = (const float*)d_in[16];
  const float* bfc  = (const float*)d_in[17];
  float* out = (float*)d_out;

  char* ws = (char*)d_ws;
  size_t o = 0;
  auto alloc = [&](size_t bytes)->char*{
    char* p = ws + o;
    o += (bytes + 255) & ~(size_t)255;
    return p;
  };
  int*    rowptr = (int*)   alloc((size_t)(NN+1)*4);
  int*    cnt    = (int*)   alloc((size_t)NN*4);
  int*    bsum   = (int*)   alloc(512*4);
  int*    boff   = (int*)   alloc(512*4);
  int*    tick   = (int*)   alloc((size_t)NE*4);
  int2*   csr2   = (int2*)  alloc((size_t)NE*8);
  float*  el     = (float*) alloc((size_t)NN*4*4);
  float*  er     = (float*) alloc((size_t)NN*4*4);
  float*  ex     = (float*) alloc((size_t)NE*4*4);     // slot-ordered softmax numerators
  ushort* xb     = (ushort*)alloc((size_t)NN*128*2);
  ushort* featb  = (ushort*)alloc((size_t)NN*128*2);
  ushort* h1b    = (ushort*)alloc((size_t)NN*128*2);
  ushort* h2b    = (ushort*)alloc((size_t)NN*128*2);
  float*  res3p  = (float*) alloc((size_t)NN*32*4);
  float*  h3     = (float*) alloc((size_t)NN*32*4);
  ushort* Bf1    = (ushort*)alloc((size_t)8*4*64*8*2);
  ushort* Bf2    = (ushort*)alloc((size_t)8*4*64*8*2);
  ushort* Bf3    = (ushort*)alloc((size_t)4*4*64*8*2);
  (void)ws_size; (void)n_in; (void)in_sizes; (void)out_size;

  // CSR build: one atomic pass (histogram+ticket), scan, atomic-free placement
  hipMemsetAsync(cnt, 0, (size_t)NN*4, stream);
  k_ticket<<<(NE+255)/256, 256, 0, stream>>>(dst, cnt, tick);
  int nb = (NN+255)/256;
  k_scan_local<<<nb, 256, 0, stream>>>(cnt, rowptr, bsum);
  k_scan_bsum<<<1, 512, 0, stream>>>(bsum, boff, nb);
  k_scan_add<<<(NN+1+255)/256, 256, 0, stream>>>(rowptr, boff);
  k_place<<<(NE+255)/256, 256, 0, stream>>>(src, dst, rowptr, tick, csr2);

  // fused x-cast + weight packs
  k_prep<<<CAST_BLOCKS+20, 256, 0, stream>>>(x, xb, W1, W2, W3, res3, Bf1, Bf2, Bf3);

  int gemm_blocks = (NN+63)/64;

  // ---- Layer 1: 128 -> 4x32, no residual, ELU ----
  k_gemm_mfma<8,8,4><<<gemm_blocks, 256, 0, stream>>>(xb, Bf1, featb, nullptr, al1, ar1, el, er, NN);
  k_edge<4><<<(NE+255)/256, 256, 0, stream>>>(csr2, el, er, ex);
  k_agg<4,0,true><<<NN/4, 256, 0, stream>>>(rowptr, csr2, featb, ex, nullptr, b1, h1b, 1);

  // ---- Layer 2: 128 -> 4x32, identity residual, ELU ----
  k_gemm_mfma<8,8,4><<<gemm_blocks, 256, 0, stream>>>(h1b, Bf2, featb, nullptr, al2, ar2, el, er, NN);
  k_edge<4><<<(NE+255)/256, 256, 0, stream>>>(csr2, el, er, ex);
  k_agg<4,1,true><<<NN/4, 256, 0, stream>>>(rowptr, csr2, featb, ex, h1b, b2, h2b, 1);

  // ---- Layer 3: fused feat3 + projected residual, 1 head, no act ----
  k_gemm_mfma<4,2,1><<<gemm_blocks, 256, 0, stream>>>(h2b, Bf3, featb, res3p, al3, ar3, el, er, NN);
  k_edge<1><<<(NE+255)/256, 256, 0, stream>>>(csr2, el, er, ex);
  k_agg<1,2,false><<<NN/4, 256, 0, stream>>>(rowptr, csr2, featb, ex, res3p, b3, h3, 0);

  // ---- classifier ----
  k_fc<<<gemm_blocks, 256, 0, stream>>>(h3, Wfc, bfc, out);
}

// Round 7
// 342.095 us; speedup vs baseline: 1.3484x; 1.0926x over previous
//
#include <hip/hip_runtime.h>
#include <cstdint>
#include <cstddef>

#define NN 100000
#define NE 1000000

typedef unsigned int uint;
typedef unsigned short ushort;
typedef __attribute__((ext_vector_type(8))) short bfrag;   // 8 bf16 = 4 VGPR
typedef __attribute__((ext_vector_type(4))) float f32x4;

__device__ __forceinline__ ushort f2bf(float f){
  uint u = __float_as_uint(f);
  u += 0x7fffu + ((u >> 16) & 1u);     // round-to-nearest-even
  return (ushort)(u >> 16);
}
__device__ __forceinline__ float bflo(uint p){ return __uint_as_float(p << 16); }
__device__ __forceinline__ float bfhi(uint p){ return __uint_as_float(p & 0xffff0000u); }

// ---------------- CSR build ----------------

__global__ __launch_bounds__(256) void k_ticket(const int* __restrict__ dst, int* __restrict__ cnt,
                                                int* __restrict__ tick){
  int e = blockIdx.x*256 + threadIdx.x;
  if (e < NE) tick[e] = atomicAdd(&cnt[dst[e]], 1);
}

__global__ __launch_bounds__(256) void k_scan_local(const int* __restrict__ cnt, int* __restrict__ rowptr,
                                                    int* __restrict__ bsum){
  __shared__ int sm[256];
  int t = threadIdx.x;
  int i = blockIdx.x*256 + t;
  int v = (i < NN) ? cnt[i] : 0;
  sm[t] = v;
  __syncthreads();
  for (int off=1; off<256; off<<=1){
    int u = (t>=off) ? sm[t-off] : 0;
    __syncthreads();
    sm[t] += u;
    __syncthreads();
  }
  if (i < NN) rowptr[i] = sm[t] - v;
  if (t == 255) bsum[blockIdx.x] = sm[255];
}

__global__ __launch_bounds__(512) void k_scan_bsum(const int* __restrict__ bsum, int* __restrict__ boff, int nb){
  __shared__ int sm[512];
  int t = threadIdx.x;
  int v = (t < nb) ? bsum[t] : 0;
  sm[t] = v;
  __syncthreads();
  for (int off=1; off<512; off<<=1){
    int u = (t>=off) ? sm[t-off] : 0;
    __syncthreads();
    sm[t] += u;
    __syncthreads();
  }
  if (t < nb) boff[t] = sm[t] - v;
}

__global__ __launch_bounds__(256) void k_scan_add(int* __restrict__ rowptr, const int* __restrict__ boff){
  int i = blockIdx.x*256 + threadIdx.x;
  if (i < NN) rowptr[i] += boff[i>>8];
  else if (i == NN) rowptr[NN] = NE;
}

// atomic-free placement; csr[slot] = src (4 B payload)
__global__ __launch_bounds__(256) void k_place(const int* __restrict__ src, const int* __restrict__ dst,
                                               const int* __restrict__ rowptr, const int* __restrict__ tick,
                                               int* __restrict__ csr){
  int e = blockIdx.x*256 + threadIdx.x;
  if (e < NE){
    int d = dst[e];
    csr[rowptr[d] + tick[e]] = src[e];
  }
}

// ---------------- fused prep: x->bf16 cast + 3 weight-fragment packs ----------------

__device__ __forceinline__ void bfrag_body(const float* __restrict__ B1, const float* __restrict__ B2,
                                           int n1, int n2, int NT, ushort* __restrict__ out, int i){
  if (i >= NT*4*64) return;
  int l = i & 63, ks = (i>>6)&3, nt = i>>8;
  int col = nt*16 + (l&15);
  int k0  = ks*32 + (l>>4)*8;
  const float* B; int stride, c;
  if (col < n1){ B = B1; stride = n1; c = col; }
  else         { B = B2; stride = n2; c = col - n1; }
  ushort v[8];
  #pragma unroll
  for (int j=0;j<8;j++) v[j] = f2bf(B[(size_t)(k0+j)*stride + c]);
  uint4 pk;
  pk.x = (uint)v[0] | ((uint)v[1]<<16);
  pk.y = (uint)v[2] | ((uint)v[3]<<16);
  pk.z = (uint)v[4] | ((uint)v[5]<<16);
  pk.w = (uint)v[6] | ((uint)v[7]<<16);
  *(uint4*)(out + (size_t)i*8) = pk;
}

#define CAST_BLOCKS 12500   // NN*128/4 / 256

__global__ __launch_bounds__(256) void k_prep(const float* __restrict__ x, ushort* __restrict__ xb,
                                              const float* __restrict__ W1, const float* __restrict__ W2,
                                              const float* __restrict__ W3, const float* __restrict__ res3,
                                              ushort* __restrict__ Bf1, ushort* __restrict__ Bf2,
                                              ushort* __restrict__ Bf3){
  int bid = blockIdx.x, t = threadIdx.x;
  if (bid < CAST_BLOCKS){
    int i = bid*256 + t;
    float4 v = ((const float4*)x)[i];
    uint2 p;
    p.x = (uint)f2bf(v.x) | ((uint)f2bf(v.y)<<16);
    p.y = (uint)f2bf(v.z) | ((uint)f2bf(v.w)<<16);
    ((uint2*)xb)[i] = p;
  } else {
    int r = bid - CAST_BLOCKS;
    if (r < 8)       bfrag_body(W1, nullptr, 128, 0, 8, Bf1, r*256 + t);
    else if (r < 16) bfrag_body(W2, nullptr, 128, 0, 8, Bf2, (r-8)*256 + t);
    else             bfrag_body(W3, res3,    32, 32, 4, Bf3, (r-16)*256 + t);
  }
}

// ---------------- MFMA GEMM, K=128, no LDS ----------------

template<int NT, int NTF, int H>
__global__ __launch_bounds__(256) void k_gemm_mfma(const ushort* __restrict__ Ab, const ushort* __restrict__ Bf,
                                                   ushort* __restrict__ featb, float* __restrict__ Cres,
                                                   const float* __restrict__ al, const float* __restrict__ ar,
                                                   float* __restrict__ el, float* __restrict__ er, int M){
  int t = threadIdx.x;
  int l = t & 63, w = t >> 6;
  int rw = blockIdx.x*64 + w*16;
  int c = l & 15, g = l >> 4;

  f32x4 acc[NT];
  #pragma unroll
  for (int nt=0;nt<NT;nt++) acc[nt] = (f32x4){0.f,0.f,0.f,0.f};

  int rowA = rw + c; if (rowA >= M) rowA = M-1;
  const ushort* Ap = Ab + (size_t)rowA*128 + g*8;
  const bfrag* Bp = (const bfrag*)Bf;

  #pragma unroll
  for (int ks=0; ks<4; ++ks){
    bfrag a = *(const bfrag*)(Ap + ks*32);
    #pragma unroll
    for (int nt=0; nt<NT; ++nt){
      bfrag b = Bp[(nt*4+ks)*64 + l];
      acc[nt] = __builtin_amdgcn_mfma_f32_16x16x32_bf16(a, b, acc[nt], 0, 0, 0);
    }
  }

  float alv[H][2], arv[H][2];
  #pragma unroll
  for (int h=0;h<H;h++){
    alv[h][0]=al[h*32+c];    arv[h][0]=ar[h*32+c];
    alv[h][1]=al[h*32+16+c]; arv[h][1]=ar[h*32+16+c];
  }

  #pragma unroll
  for (int reg=0; reg<4; ++reg){
    int row = rw + g*4 + reg;
    bool ok = row < M;
    #pragma unroll
    for (int h=0;h<H;h++){
      float pl = acc[2*h][reg]*alv[h][0] + acc[2*h+1][reg]*alv[h][1];
      float pr = acc[2*h][reg]*arv[h][0] + acc[2*h+1][reg]*arv[h][1];
      #pragma unroll
      for (int off=1; off<16; off<<=1){ pl += __shfl_xor(pl,off); pr += __shfl_xor(pr,off); }
      if (ok && c==0){ el[(size_t)row*H + h] = pl; er[(size_t)row*H + h] = pr; }
    }
    if (ok){
      #pragma unroll
      for (int nt=0; nt<NTF; ++nt)
        featb[(size_t)row*(NTF*16) + nt*16 + c] = f2bf(acc[nt][reg]);
      #pragma unroll
      for (int nt=NTF; nt<NT; ++nt)
        Cres[(size_t)row*((NT-NTF)*16) + (nt-NTF)*16 + c] = acc[nt][reg];
    }
  }
}

// ---------------- aggregation H=4: fused edge-softmax + gather ----------------
// pass1: gather el[src] (L2-resident), ex = exp(leaky(el+er)) -> per-wave LDS (deg<=64) + sum.
// pass2: 2 edges/iter across lane halves, uint2 (4 bf16) per lane, shfl_xor(32) combine.
// RK: 0=none 1=bf16 2=fp32 residual. OBF: bf16 output.

template<int RK, bool OBF>
__global__ __launch_bounds__(256) void k_agg4(const int* __restrict__ rowptr, const int* __restrict__ csr,
                                              const ushort* __restrict__ feat,
                                              const float* __restrict__ el, const float* __restrict__ er,
                                              const void* __restrict__ res, const float* __restrict__ bias,
                                              void* __restrict__ out, int act){
  __shared__ float exs[4][256];          // per-wave: 64 edges x 4 heads
  int lane = threadIdx.x & 63;
  int wloc = threadIdx.x >> 6;
  int node = blockIdx.x*4 + wloc;

  int beg = rowptr[node], deg = rowptr[node+1] - beg;
  bool fits = (deg <= 64);               // Poisson(10): max deg ~30; fallback below is exact anyway

  // ---- pass 1: ex + per-head sums ----
  float erA = er[(size_t)node*4 + (lane&3)];
  float ssum = 0.f;
  for (int idx = lane; idx < deg*4; idx += 64){
    int s = csr[beg + (idx>>2)];
    float v = el[(size_t)s*4 + (idx&3)] + erA;
    v = (v>0.f) ? v : 0.2f*v;
    float e = __expf(v);
    if (fits) exs[wloc][idx] = e;
    ssum += e;
  }
  #pragma unroll
  for (int off=4; off<64; off<<=1) ssum += __shfl_xor(ssum, off);

  int l31 = lane & 31;
  int hm  = l31 >> 3;                    // head owning this lane's 4 features
  float sg  = __shfl(ssum, hm);
  float inv = (deg > 0) ? 1.f/sg : 0.f;
  int half = lane >> 5;
  int nE = (deg - half + 1) >> 1;        // half0: even edges, half1: odd edges

  // ---- pass 2: gather-accumulate, 2 edges per wave-iter ----
  const ushort* fbase = feat + (size_t)l31*4;
  float a0=0.f, a1=0.f, a2=0.f, a3=0.f;

  if (fits){
    int i = 0;
    for (; i+4 <= nE; i += 4){
      int e0 = 2*i+half, e1 = e0+2, e2 = e0+4, e3 = e0+6;
      int s0 = csr[beg+e0], s1 = csr[beg+e1], s2 = csr[beg+e2], s3 = csr[beg+e3];
      uint2 p0 = *(const uint2*)(fbase + (size_t)s0*128);
      uint2 p1 = *(const uint2*)(fbase + (size_t)s1*128);
      uint2 p2 = *(const uint2*)(fbase + (size_t)s2*128);
      uint2 p3 = *(const uint2*)(fbase + (size_t)s3*128);
      float w0 = exs[wloc][e0*4+hm]*inv, w1 = exs[wloc][e1*4+hm]*inv;
      float w2 = exs[wloc][e2*4+hm]*inv, w3 = exs[wloc][e3*4+hm]*inv;
      a0 += w0*bflo(p0.x) + w1*bflo(p1.x) + w2*bflo(p2.x) + w3*bflo(p3.x);
      a1 += w0*bfhi(p0.x) + w1*bfhi(p1.x) + w2*bfhi(p2.x) + w3*bfhi(p3.x);
      a2 += w0*bflo(p0.y) + w1*bflo(p1.y) + w2*bflo(p2.y) + w3*bflo(p3.y);
      a3 += w0*bfhi(p0.y) + w1*bfhi(p1.y) + w2*bfhi(p2.y) + w3*bfhi(p3.y);
    }
    for (; i < nE; ++i){
      int e0 = 2*i+half;
      int s0 = csr[beg+e0];
      uint2 p0 = *(const uint2*)(fbase + (size_t)s0*128);
      float w0 = exs[wloc][e0*4+hm]*inv;
      a0 += w0*bflo(p0.x); a1 += w0*bfhi(p0.x);
      a2 += w0*bflo(p0.y); a3 += w0*bfhi(p0.y);
    }
  } else {
    float erh = er[(size_t)node*4 + hm];
    for (int i = 0; i < nE; ++i){
      int e0 = 2*i+half;
      int s0 = csr[beg+e0];
      uint2 p0 = *(const uint2*)(fbase + (size_t)s0*128);
      float v = el[(size_t)s0*4 + hm] + erh;
      v = (v>0.f) ? v : 0.2f*v;
      float w0 = __expf(v)*inv;
      a0 += w0*bflo(p0.x); a1 += w0*bfhi(p0.x);
      a2 += w0*bflo(p0.y); a3 += w0*bfhi(p0.y);
    }
  }

  a0 += __shfl_xor(a0, 32); a1 += __shfl_xor(a1, 32);
  a2 += __shfl_xor(a2, 32); a3 += __shfl_xor(a3, 32);

  if (lane < 32){
    float o0=a0, o1=a1, o2=a2, o3=a3;
    if (RK == 1){
      uint2 rv = *(const uint2*)((const ushort*)res + (size_t)node*128 + lane*4);
      o0 += bflo(rv.x); o1 += bfhi(rv.x); o2 += bflo(rv.y); o3 += bfhi(rv.y);
    } else if (RK == 2){
      float4 rv = *(const float4*)((const float*)res + (size_t)node*128 + lane*4);
      o0 += rv.x; o1 += rv.y; o2 += rv.z; o3 += rv.w;
    }
    float4 bv = *(const float4*)(bias + lane*4);
    o0 += bv.x; o1 += bv.y; o2 += bv.z; o3 += bv.w;
    if (act){
      o0 = (o0>0.f)?o0:__expf(o0)-1.f;
      o1 = (o1>0.f)?o1:__expf(o1)-1.f;
      o2 = (o2>0.f)?o2:__expf(o2)-1.f;
      o3 = (o3>0.f)?o3:__expf(o3)-1.f;
    }
    if (OBF){
      uint2 pk;
      pk.x = (uint)f2bf(o0) | ((uint)f2bf(o1)<<16);
      pk.y = (uint)f2bf(o2) | ((uint)f2bf(o3)<<16);
      *(uint2*)((ushort*)out + (size_t)node*128 + lane*4) = pk;
    } else {
      float4 ov; ov.x=o0; ov.y=o1; ov.z=o2; ov.w=o3;
      *(float4*)((float*)out + (size_t)node*128 + lane*4) = ov;
    }
  }
}

// ---------------- aggregation H=1 + fused final FC ----------------
// o[32] = segsum(alpha*feat) + res3p + b3; out[node,40] = o @ Wfc + bfc.

__global__ __launch_bounds__(256) void k_agg1fc(const int* __restrict__ rowptr, const int* __restrict__ csr,
                                                const ushort* __restrict__ feat,
                                                const float* __restrict__ el, const float* __restrict__ er,
                                                const float* __restrict__ res, const float* __restrict__ bias,
                                                const float* __restrict__ Wfc, const float* __restrict__ bfc,
                                                float* __restrict__ out){
  __shared__ float exs[4][128];
  int lane = threadIdx.x & 63;
  int wloc = threadIdx.x >> 6;
  int node = blockIdx.x*4 + wloc;

  int beg = rowptr[node], deg = rowptr[node+1] - beg;
  bool fits = (deg <= 128);

  // ---- pass 1 ----
  float er0 = er[node];
  float ssum = 0.f;
  for (int idx = lane; idx < deg; idx += 64){
    int s = csr[beg + idx];
    float v = el[s] + er0;
    v = (v>0.f) ? v : 0.2f*v;
    float e = __expf(v);
    if (fits) exs[wloc][idx] = e;
    ssum += e;
  }
  #pragma unroll
  for (int off=1; off<64; off<<=1) ssum += __shfl_xor(ssum, off);
  float inv = (deg > 0) ? 1.f/ssum : 0.f;

  // ---- pass 2: 8 edge-substreams x 8 lanes (4 feats each) ----
  int grp = lane >> 3, fl = lane & 7;
  const ushort* fbase = feat + (size_t)fl*4;
  float a0=0.f, a1=0.f, a2=0.f, a3=0.f;
  if (fits){
    #pragma unroll 2
    for (int ei = grp; ei < deg; ei += 8){
      int s = csr[beg + ei];
      uint2 pv = *(const uint2*)(fbase + (size_t)s*32);
      float w = exs[wloc][ei]*inv;
      a0 += w*bflo(pv.x); a1 += w*bfhi(pv.x);
      a2 += w*bflo(pv.y); a3 += w*bfhi(pv.y);
    }
  } else {
    for (int ei = grp; ei < deg; ei += 8){
      int s = csr[beg + ei];
      uint2 pv = *(const uint2*)(fbase + (size_t)s*32);
      float v = el[s] + er0;
      v = (v>0.f) ? v : 0.2f*v;
      float w = __expf(v)*inv;
      a0 += w*bflo(pv.x); a1 += w*bfhi(pv.x);
      a2 += w*bflo(pv.y); a3 += w*bfhi(pv.y);
    }
  }
  #pragma unroll
  for (int off=8; off<64; off<<=1){
    a0 += __shfl_xor(a0, off); a1 += __shfl_xor(a1, off);
    a2 += __shfl_xor(a2, off); a3 += __shfl_xor(a3, off);
  }

  // residual + bias (features 4*fl .. 4*fl+3), all lanes (values replicated across groups)
  {
    float4 rv = *(const float4*)(res + (size_t)node*32 + fl*4);
    float4 bv = *(const float4*)(bias + fl*4);
    a0 += rv.x + bv.x; a1 += rv.y + bv.y;
    a2 += rv.z + bv.z; a3 += rv.w + bv.w;
  }

  // ---- fused FC: out[node, j] = sum_k o[k]*Wfc[k*40+j] + bfc[j], j = lane < 40 ----
  float acc = 0.f;
  #pragma unroll
  for (int k = 0; k < 32; ++k){
    int q = k >> 2, r = k & 3;
    float ok;
    if      (r == 0) ok = __shfl(a0, q);
    else if (r == 1) ok = __shfl(a1, q);
    else if (r == 2) ok = __shfl(a2, q);
    else             ok = __shfl(a3, q);
    acc += ok * Wfc[k*40 + lane];        // lane < 40 used; others read junk harmlessly in-bounds? guard below
  }
  if (lane < 40)
    out[(size_t)node*40 + lane] = acc + bfc[lane];
}

// ---------------- launch ----------------

extern "C" void kernel_launch(void* const* d_in, const int* in_sizes, int n_in,
                              void* d_out, int out_size, void* d_ws, size_t ws_size,
                              hipStream_t stream){
  const float* x    = (const float*)d_in[0];
  const int*   src  = (const int*)  d_in[1];
  const int*   dst  = (const int*)  d_in[2];
  const float* W1   = (const float*)d_in[3];
  const float* al1  = (const float*)d_in[4];
  const float* ar1  = (const float*)d_in[5];
  const float* b1   = (const float*)d_in[6];
  const float* W2   = (const float*)d_in[7];
  const float* al2  = (const float*)d_in[8];
  const float* ar2  = (const float*)d_in[9];
  const float* b2   = (const float*)d_in[10];
  const float* W3   = (const float*)d_in[11];
  const float* al3  = (const float*)d_in[12];
  const float* ar3  = (const float*)d_in[13];
  const float* b3   = (const float*)d_in[14];
  const float* res3 = (const float*)d_in[15];
  const float* Wfc  = (const float*)d_in[16];
  const float* bfc  = (const float*)d_in[17];
  float* out = (float*)d_out;

  char* ws = (char*)d_ws;
  size_t o = 0;
  auto alloc = [&](size_t bytes)->char*{
    char* p = ws + o;
    o += (bytes + 255) & ~(size_t)255;
    return p;
  };
  int*    rowptr = (int*)   alloc((size_t)(NN+1)*4);
  int*    cnt    = (int*)   alloc((size_t)NN*4);
  int*    bsum   = (int*)   alloc(512*4);
  int*    boff   = (int*)   alloc(512*4);
  int*    tick   = (int*)   alloc((size_t)NE*4);
  int*    csr    = (int*)   alloc((size_t)NE*4);
  float*  el     = (float*) alloc((size_t)NN*4*4);
  float*  er     = (float*) alloc((size_t)NN*4*4);
  ushort* xb     = (ushort*)alloc((size_t)NN*128*2);
  ushort* featb  = (ushort*)alloc((size_t)NN*128*2);
  ushort* h1b    = (ushort*)alloc((size_t)NN*128*2);
  ushort* h2b    = (ushort*)alloc((size_t)NN*128*2);
  float*  res3p  = (float*) alloc((size_t)NN*32*4);
  ushort* Bf1    = (ushort*)alloc((size_t)8*4*64*8*2);
  ushort* Bf2    = (ushort*)alloc((size_t)8*4*64*8*2);
  ushort* Bf3    = (ushort*)alloc((size_t)4*4*64*8*2);
  (void)ws_size; (void)n_in; (void)in_sizes; (void)out_size;

  // CSR build: one atomic pass (histogram+ticket), scan, atomic-free placement
  hipMemsetAsync(cnt, 0, (size_t)NN*4, stream);
  k_ticket<<<(NE+255)/256, 256, 0, stream>>>(dst, cnt, tick);
  int nb = (NN+255)/256;
  k_scan_local<<<nb, 256, 0, stream>>>(cnt, rowptr, bsum);
  k_scan_bsum<<<1, 512, 0, stream>>>(bsum, boff, nb);
  k_scan_add<<<(NN+1+255)/256, 256, 0, stream>>>(rowptr, boff);
  k_place<<<(NE+255)/256, 256, 0, stream>>>(src, dst, rowptr, tick, csr);

  // fused x-cast + weight packs
  k_prep<<<CAST_BLOCKS+20, 256, 0, stream>>>(x, xb, W1, W2, W3, res3, Bf1, Bf2, Bf3);

  int gemm_blocks = (NN+63)/64;

  // ---- Layer 1: 128 -> 4x32, no residual, ELU ----
  k_gemm_mfma<8,8,4><<<gemm_blocks, 256, 0, stream>>>(xb, Bf1, featb, nullptr, al1, ar1, el, er, NN);
  k_agg4<0,true><<<NN/4, 256, 0, stream>>>(rowptr, csr, featb, el, er, nullptr, b1, h1b, 1);

  // ---- Layer 2: 128 -> 4x32, identity residual, ELU ----
  k_gemm_mfma<8,8,4><<<gemm_blocks, 256, 0, stream>>>(h1b, Bf2, featb, nullptr, al2, ar2, el, er, NN);
  k_agg4<1,true><<<NN/4, 256, 0, stream>>>(rowptr, csr, featb, el, er, h1b, b2, h2b, 1);

  // ---- Layer 3: fused feat3 + projected residual + agg + classifier ----
  k_gemm_mfma<4,2,1><<<gemm_blocks, 256, 0, stream>>>(h2b, Bf3, featb, res3p, al3, ar3, el, er, NN);
  k_agg1fc<<<NN/4, 256, 0, stream>>>(rowptr, csr, featb, el, er, res3p, b3, Wfc, bfc, out);
}

// Round 8
// 321.361 us; speedup vs baseline: 1.4354x; 1.0645x over previous
//
#include <hip/hip_runtime.h>
#include <cstdint>
#include <cstddef>

#define NN 100000
#define NE 1000000

typedef unsigned int uint;
typedef unsigned short ushort;
typedef __attribute__((ext_vector_type(8))) short bfrag;   // 8 bf16 = 4 VGPR
typedef __attribute__((ext_vector_type(4))) float f32x4;

__device__ __forceinline__ ushort f2bf(float f){
  uint u = __float_as_uint(f);
  u += 0x7fffu + ((u >> 16) & 1u);     // round-to-nearest-even
  return (ushort)(u >> 16);
}
__device__ __forceinline__ float bflo(uint p){ return __uint_as_float(p << 16); }
__device__ __forceinline__ float bfhi(uint p){ return __uint_as_float(p & 0xffff0000u); }

// ---------------- CSR build ----------------

__global__ __launch_bounds__(256) void k_ticket(const int* __restrict__ dst, int* __restrict__ cnt,
                                                int* __restrict__ tick){
  int e = blockIdx.x*256 + threadIdx.x;
  if (e < NE) tick[e] = atomicAdd(&cnt[dst[e]], 1);
}

__global__ __launch_bounds__(256) void k_scan_local(const int* __restrict__ cnt, int* __restrict__ rowptr,
                                                    int* __restrict__ bsum){
  __shared__ int sm[256];
  int t = threadIdx.x;
  int i = blockIdx.x*256 + t;
  int v = (i < NN) ? cnt[i] : 0;
  sm[t] = v;
  __syncthreads();
  for (int off=1; off<256; off<<=1){
    int u = (t>=off) ? sm[t-off] : 0;
    __syncthreads();
    sm[t] += u;
    __syncthreads();
  }
  if (i < NN) rowptr[i] = sm[t] - v;
  if (t == 255) bsum[blockIdx.x] = sm[255];
}

__global__ __launch_bounds__(512) void k_scan_bsum(const int* __restrict__ bsum, int* __restrict__ boff, int nb){
  __shared__ int sm[512];
  int t = threadIdx.x;
  int v = (t < nb) ? bsum[t] : 0;
  sm[t] = v;
  __syncthreads();
  for (int off=1; off<512; off<<=1){
    int u = (t>=off) ? sm[t-off] : 0;
    __syncthreads();
    sm[t] += u;
    __syncthreads();
  }
  if (t < nb) boff[t] = sm[t] - v;
}

__global__ __launch_bounds__(256) void k_scan_add(int* __restrict__ rowptr, const int* __restrict__ boff){
  int i = blockIdx.x*256 + threadIdx.x;
  if (i < NN) rowptr[i] += boff[i>>8];
  else if (i == NN) rowptr[NN] = NE;
}

__global__ __launch_bounds__(256) void k_place(const int* __restrict__ src, const int* __restrict__ dst,
                                               const int* __restrict__ rowptr, const int* __restrict__ tick,
                                               int* __restrict__ csr){
  int e = blockIdx.x*256 + threadIdx.x;
  if (e < NE){
    int d = dst[e];
    csr[rowptr[d] + tick[e]] = src[e];
  }
}

// ---------------- fused prep: x->bf16 cast + 3 weight-fragment packs ----------------

__device__ __forceinline__ void bfrag_body(const float* __restrict__ B1, const float* __restrict__ B2,
                                           int n1, int n2, int NT, ushort* __restrict__ out, int i){
  if (i >= NT*4*64) return;
  int l = i & 63, ks = (i>>6)&3, nt = i>>8;
  int col = nt*16 + (l&15);
  int k0  = ks*32 + (l>>4)*8;
  const float* B; int stride, c;
  if (col < n1){ B = B1; stride = n1; c = col; }
  else         { B = B2; stride = n2; c = col - n1; }
  ushort v[8];
  #pragma unroll
  for (int j=0;j<8;j++) v[j] = f2bf(B[(size_t)(k0+j)*stride + c]);
  uint4 pk;
  pk.x = (uint)v[0] | ((uint)v[1]<<16);
  pk.y = (uint)v[2] | ((uint)v[3]<<16);
  pk.z = (uint)v[4] | ((uint)v[5]<<16);
  pk.w = (uint)v[6] | ((uint)v[7]<<16);
  *(uint4*)(out + (size_t)i*8) = pk;
}

#define CAST_BLOCKS 12500   // NN*128/4 / 256

__global__ __launch_bounds__(256) void k_prep(const float* __restrict__ x, ushort* __restrict__ xb,
                                              const float* __restrict__ W1, const float* __restrict__ W2,
                                              const float* __restrict__ W3, const float* __restrict__ res3,
                                              ushort* __restrict__ Bf1, ushort* __restrict__ Bf2,
                                              ushort* __restrict__ Bf3){
  int bid = blockIdx.x, t = threadIdx.x;
  if (bid < CAST_BLOCKS){
    int i = bid*256 + t;
    float4 v = ((const float4*)x)[i];
    uint2 p;
    p.x = (uint)f2bf(v.x) | ((uint)f2bf(v.y)<<16);
    p.y = (uint)f2bf(v.z) | ((uint)f2bf(v.w)<<16);
    ((uint2*)xb)[i] = p;
  } else {
    int r = bid - CAST_BLOCKS;
    if (r < 8)       bfrag_body(W1, nullptr, 128, 0, 8, Bf1, r*256 + t);
    else if (r < 16) bfrag_body(W2, nullptr, 128, 0, 8, Bf2, (r-8)*256 + t);
    else             bfrag_body(W3, res3,    32, 32, 4, Bf3, (r-16)*256 + t);
  }
}

// ---------------- MFMA GEMM, K=128, no LDS ----------------

template<int NT, int NTF, int H>
__global__ __launch_bounds__(256) void k_gemm_mfma(const ushort* __restrict__ Ab, const ushort* __restrict__ Bf,
                                                   ushort* __restrict__ featb, float* __restrict__ Cres,
                                                   const float* __restrict__ al, const float* __restrict__ ar,
                                                   float* __restrict__ el, float* __restrict__ er, int M){
  int t = threadIdx.x;
  int l = t & 63, w = t >> 6;
  int rw = blockIdx.x*64 + w*16;
  int c = l & 15, g = l >> 4;

  f32x4 acc[NT];
  #pragma unroll
  for (int nt=0;nt<NT;nt++) acc[nt] = (f32x4){0.f,0.f,0.f,0.f};

  int rowA = rw + c; if (rowA >= M) rowA = M-1;
  const ushort* Ap = Ab + (size_t)rowA*128 + g*8;
  const bfrag* Bp = (const bfrag*)Bf;

  #pragma unroll
  for (int ks=0; ks<4; ++ks){
    bfrag a = *(const bfrag*)(Ap + ks*32);
    #pragma unroll
    for (int nt=0; nt<NT; ++nt){
      bfrag b = Bp[(nt*4+ks)*64 + l];
      acc[nt] = __builtin_amdgcn_mfma_f32_16x16x32_bf16(a, b, acc[nt], 0, 0, 0);
    }
  }

  float alv[H][2], arv[H][2];
  #pragma unroll
  for (int h=0;h<H;h++){
    alv[h][0]=al[h*32+c];    arv[h][0]=ar[h*32+c];
    alv[h][1]=al[h*32+16+c]; arv[h][1]=ar[h*32+16+c];
  }

  #pragma unroll
  for (int reg=0; reg<4; ++reg){
    int row = rw + g*4 + reg;
    bool ok = row < M;
    #pragma unroll
    for (int h=0;h<H;h++){
      float pl = acc[2*h][reg]*alv[h][0] + acc[2*h+1][reg]*alv[h][1];
      float pr = acc[2*h][reg]*arv[h][0] + acc[2*h+1][reg]*arv[h][1];
      #pragma unroll
      for (int off=1; off<16; off<<=1){ pl += __shfl_xor(pl,off); pr += __shfl_xor(pr,off); }
      if (ok && c==0){ el[(size_t)row*H + h] = pl; er[(size_t)row*H + h] = pr; }
    }
    if (ok){
      #pragma unroll
      for (int nt=0; nt<NTF; ++nt)
        featb[(size_t)row*(NTF*16) + nt*16 + c] = f2bf(acc[nt][reg]);
      #pragma unroll
      for (int nt=NTF; nt<NT; ++nt)
        Cres[(size_t)row*((NT-NTF)*16) + (nt-NTF)*16 + c] = acc[nt][reg];
    }
  }
}

// ---------------- aggregation H=4: SINGLE-PASS fused softmax+gather ----------------
// out = (sum_e ex_e * feat_e) / (sum_e ex_e) -- accumulate both in one edge loop.
// 2 edges/iter across lane halves; lane l31 owns feats 4*l31.., head hm = l31>>3.
// RK: 0=none 1=bf16 2=fp32 residual. OBF: bf16 output.

template<int RK, bool OBF>
__global__ __launch_bounds__(256) void k_agg4(const int* __restrict__ rowptr, const int* __restrict__ csr,
                                              const ushort* __restrict__ feat,
                                              const float* __restrict__ el, const float* __restrict__ er,
                                              const void* __restrict__ res, const float* __restrict__ bias,
                                              void* __restrict__ out, int act){
  int lane = threadIdx.x & 63;
  int node = blockIdx.x*4 + (threadIdx.x >> 6);

  int beg = rowptr[node], deg = rowptr[node+1] - beg;

  int l31 = lane & 31;
  int hm  = l31 >> 3;
  int half = lane >> 5;
  float erh = er[(size_t)node*4 + hm];
  const ushort* fbase = feat + (size_t)l31*4;
  const int* cp = csr + beg;

  float ssum = 0.f;
  float a0=0.f, a1=0.f, a2=0.f, a3=0.f;
  int nE = (deg - half + 1) >> 1;        // this half's edges: half, half+2, ...

  int i = 0;
  for (; i+4 <= nE; i += 4){
    int e0 = 2*i+half, e1 = e0+2, e2 = e0+4, e3 = e0+6;
    int s0 = cp[e0], s1 = cp[e1], s2 = cp[e2], s3 = cp[e3];
    uint2 p0 = *(const uint2*)(fbase + (size_t)s0*128);
    uint2 p1 = *(const uint2*)(fbase + (size_t)s1*128);
    uint2 p2 = *(const uint2*)(fbase + (size_t)s2*128);
    uint2 p3 = *(const uint2*)(fbase + (size_t)s3*128);
    float v0 = el[(size_t)s0*4+hm] + erh; v0=(v0>0.f)?v0:0.2f*v0; float w0=__expf(v0);
    float v1 = el[(size_t)s1*4+hm] + erh; v1=(v1>0.f)?v1:0.2f*v1; float w1=__expf(v1);
    float v2 = el[(size_t)s2*4+hm] + erh; v2=(v2>0.f)?v2:0.2f*v2; float w2=__expf(v2);
    float v3 = el[(size_t)s3*4+hm] + erh; v3=(v3>0.f)?v3:0.2f*v3; float w3=__expf(v3);
    ssum += w0+w1+w2+w3;
    a0 += w0*bflo(p0.x) + w1*bflo(p1.x) + w2*bflo(p2.x) + w3*bflo(p3.x);
    a1 += w0*bfhi(p0.x) + w1*bfhi(p1.x) + w2*bfhi(p2.x) + w3*bfhi(p3.x);
    a2 += w0*bflo(p0.y) + w1*bflo(p1.y) + w2*bflo(p2.y) + w3*bflo(p3.y);
    a3 += w0*bfhi(p0.y) + w1*bfhi(p1.y) + w2*bfhi(p2.y) + w3*bfhi(p3.y);
  }
  for (; i < nE; ++i){
    int e0 = 2*i+half;
    int s0 = cp[e0];
    uint2 p0 = *(const uint2*)(fbase + (size_t)s0*128);
    float v0 = el[(size_t)s0*4+hm] + erh; v0=(v0>0.f)?v0:0.2f*v0; float w0=__expf(v0);
    ssum += w0;
    a0 += w0*bflo(p0.x); a1 += w0*bfhi(p0.x);
    a2 += w0*bflo(p0.y); a3 += w0*bfhi(p0.y);
  }

  // combine halves (partner lane has same l31/hm, other edge parity)
  ssum += __shfl_xor(ssum, 32);
  a0 += __shfl_xor(a0, 32); a1 += __shfl_xor(a1, 32);
  a2 += __shfl_xor(a2, 32); a3 += __shfl_xor(a3, 32);
  float inv = (deg > 0) ? 1.f/ssum : 0.f;
  a0 *= inv; a1 *= inv; a2 *= inv; a3 *= inv;

  if (lane < 32){
    float o0=a0, o1=a1, o2=a2, o3=a3;
    if (RK == 1){
      uint2 rv = *(const uint2*)((const ushort*)res + (size_t)node*128 + lane*4);
      o0 += bflo(rv.x); o1 += bfhi(rv.x); o2 += bflo(rv.y); o3 += bfhi(rv.y);
    } else if (RK == 2){
      float4 rv = *(const float4*)((const float*)res + (size_t)node*128 + lane*4);
      o0 += rv.x; o1 += rv.y; o2 += rv.z; o3 += rv.w;
    }
    float4 bv = *(const float4*)(bias + lane*4);
    o0 += bv.x; o1 += bv.y; o2 += bv.z; o3 += bv.w;
    if (act){
      o0 = (o0>0.f)?o0:__expf(o0)-1.f;
      o1 = (o1>0.f)?o1:__expf(o1)-1.f;
      o2 = (o2>0.f)?o2:__expf(o2)-1.f;
      o3 = (o3>0.f)?o3:__expf(o3)-1.f;
    }
    if (OBF){
      uint2 pk;
      pk.x = (uint)f2bf(o0) | ((uint)f2bf(o1)<<16);
      pk.y = (uint)f2bf(o2) | ((uint)f2bf(o3)<<16);
      *(uint2*)((ushort*)out + (size_t)node*128 + lane*4) = pk;
    } else {
      float4 ov; ov.x=o0; ov.y=o1; ov.z=o2; ov.w=o3;
      *(float4*)((float*)out + (size_t)node*128 + lane*4) = ov;
    }
  }
}

// ---------------- aggregation H=1: single-pass, writes h3 fp32 ----------------
// 4 edge substreams x 16 lanes (2 feats each). res fp32, bias, no activation.

__global__ __launch_bounds__(256) void k_agg1(const int* __restrict__ rowptr, const int* __restrict__ csr,
                                              const ushort* __restrict__ feat,
                                              const float* __restrict__ el, const float* __restrict__ er,
                                              const float* __restrict__ res, const float* __restrict__ bias,
                                              float* __restrict__ h3){
  int lane = threadIdx.x & 63;
  int node = blockIdx.x*4 + (threadIdx.x >> 6);

  int beg = rowptr[node], deg = rowptr[node+1] - beg;
  int sub = lane >> 4, fl = lane & 15;
  float er0 = er[node];
  const ushort* fbase = feat + (size_t)fl*2;
  const int* cp = csr + beg;

  float ssum = 0.f, a0 = 0.f, a1 = 0.f;
  for (int ei = sub; ei < deg; ei += 4){
    int s = cp[ei];
    uint pv = *(const uint*)(fbase + (size_t)s*32);
    float v = el[s] + er0; v = (v>0.f)?v:0.2f*v;
    float w = __expf(v);
    ssum += w;
    a0 += w*bflo(pv); a1 += w*bfhi(pv);
  }
  ssum += __shfl_xor(ssum, 16); ssum += __shfl_xor(ssum, 32);
  a0 += __shfl_xor(a0, 16); a0 += __shfl_xor(a0, 32);
  a1 += __shfl_xor(a1, 16); a1 += __shfl_xor(a1, 32);
  float inv = (deg > 0) ? 1.f/ssum : 0.f;

  if (lane < 16){
    float2 rv = *(const float2*)(res + (size_t)node*32 + 2*fl);
    float o0 = a0*inv + rv.x + bias[2*fl];
    float o1 = a1*inv + rv.y + bias[2*fl+1];
    float2 ov; ov.x = o0; ov.y = o1;
    *(float2*)(h3 + (size_t)node*32 + 2*fl) = ov;
  }
}

// ---------------- final FC: out[N,40] = h[N,32] @ Wfc[32,40] + bfc ----------------

__global__ __launch_bounds__(256) void k_fc(const float* __restrict__ h, const float* __restrict__ W,
                                            const float* __restrict__ b, float* __restrict__ out){
  __shared__ float Ws[32*40];
  __shared__ float Hs[64][33];
  __shared__ float bs[40];
  int t = threadIdx.x;
  for (int i=t; i<1280; i+=256) Ws[i] = W[i];
  if (t < 40) bs[t] = b[t];
  int n0 = blockIdx.x*64;
  for (int idx=t; idx<512; idx+=256){
    int r = idx>>3, c4 = idx&7;
    float4 v;
    if (n0 + r < NN) v = *(const float4*)(h + (size_t)(n0+r)*32 + c4*4);
    else v = make_float4(0.f,0.f,0.f,0.f);
    Hs[r][c4*4+0]=v.x; Hs[r][c4*4+1]=v.y; Hs[r][c4*4+2]=v.z; Hs[r][c4*4+3]=v.w;
  }
  __syncthreads();
  int n = t>>2, cg = t&3;
  float acc[10];
  #pragma unroll
  for (int j=0;j<10;j++) acc[j] = 0.f;
  #pragma unroll
  for (int k=0;k<32;k++){
    float hv = Hs[n][k];
    #pragma unroll
    for (int j=0;j<10;j++) acc[j] += hv * Ws[k*40 + cg + 4*j];
  }
  int row = n0 + n;
  if (row < NN){
    #pragma unroll
    for (int j=0;j<10;j++) out[(size_t)row*40 + cg + 4*j] = acc[j] + bs[cg+4*j];
  }
}

// ---------------- launch ----------------

extern "C" void kernel_launch(void* const* d_in, const int* in_sizes, int n_in,
                              void* d_out, int out_size, void* d_ws, size_t ws_size,
                              hipStream_t stream){
  const float* x    = (const float*)d_in[0];
  const int*   src  = (const int*)  d_in[1];
  const int*   dst  = (const int*)  d_in[2];
  const float* W1   = (const float*)d_in[3];
  const float* al1  = (const float*)d_in[4];
  const float* ar1  = (const float*)d_in[5];
  const float* b1   = (const float*)d_in[6];
  const float* W2   = (const float*)d_in[7];
  const float* al2  = (const float*)d_in[8];
  const float* ar2  = (const float*)d_in[9];
  const float* b2   = (const float*)d_in[10];
  const float* W3   = (const float*)d_in[11];
  const float* al3  = (const float*)d_in[12];
  const float* ar3  = (const float*)d_in[13];
  const float* b3   = (const float*)d_in[14];
  const float* res3 = (const float*)d_in[15];
  const float* Wfc  = (const float*)d_in[16];
  const float* bfc  = (const float*)d_in[17];
  float* out = (float*)d_out;

  char* ws = (char*)d_ws;
  size_t o = 0;
  auto alloc = [&](size_t bytes)->char*{
    char* p = ws + o;
    o += (bytes + 255) & ~(size_t)255;
    return p;
  };
  int*    rowptr = (int*)   alloc((size_t)(NN+1)*4);
  int*    cnt    = (int*)   alloc((size_t)NN*4);
  int*    bsum   = (int*)   alloc(512*4);
  int*    boff   = (int*)   alloc(512*4);
  int*    tick   = (int*)   alloc((size_t)NE*4);
  int*    csr    = (int*)   alloc((size_t)NE*4);
  float*  el     = (float*) alloc((size_t)NN*4*4);
  float*  er     = (float*) alloc((size_t)NN*4*4);
  ushort* xb     = (ushort*)alloc((size_t)NN*128*2);
  ushort* featb  = (ushort*)alloc((size_t)NN*128*2);
  ushort* h1b    = (ushort*)alloc((size_t)NN*128*2);
  ushort* h2b    = (ushort*)alloc((size_t)NN*128*2);
  float*  res3p  = (float*) alloc((size_t)NN*32*4);
  float*  h3     = (float*) alloc((size_t)NN*32*4);
  ushort* Bf1    = (ushort*)alloc((size_t)8*4*64*8*2);
  ushort* Bf2    = (ushort*)alloc((size_t)8*4*64*8*2);
  ushort* Bf3    = (ushort*)alloc((size_t)4*4*64*8*2);
  (void)ws_size; (void)n_in; (void)in_sizes; (void)out_size;

  // CSR build: one atomic pass (histogram+ticket), scan, atomic-free placement
  hipMemsetAsync(cnt, 0, (size_t)NN*4, stream);
  k_ticket<<<(NE+255)/256, 256, 0, stream>>>(dst, cnt, tick);
  int nb = (NN+255)/256;
  k_scan_local<<<nb, 256, 0, stream>>>(cnt, rowptr, bsum);
  k_scan_bsum<<<1, 512, 0, stream>>>(bsum, boff, nb);
  k_scan_add<<<(NN+1+255)/256, 256, 0, stream>>>(rowptr, boff);
  k_place<<<(NE+255)/256, 256, 0, stream>>>(src, dst, rowptr, tick, csr);

  // fused x-cast + weight packs
  k_prep<<<CAST_BLOCKS+20, 256, 0, stream>>>(x, xb, W1, W2, W3, res3, Bf1, Bf2, Bf3);

  int gemm_blocks = (NN+63)/64;

  // ---- Layer 1: 128 -> 4x32, no residual, ELU ----
  k_gemm_mfma<8,8,4><<<gemm_blocks, 256, 0, stream>>>(xb, Bf1, featb, nullptr, al1, ar1, el, er, NN);
  k_agg4<0,true><<<NN/4, 256, 0, stream>>>(rowptr, csr, featb, el, er, nullptr, b1, h1b, 1);

  // ---- Layer 2: 128 -> 4x32, identity residual, ELU ----
  k_gemm_mfma<8,8,4><<<gemm_blocks, 256, 0, stream>>>(h1b, Bf2, featb, nullptr, al2, ar2, el, er, NN);
  k_agg4<1,true><<<NN/4, 256, 0, stream>>>(rowptr, csr, featb, el, er, h1b, b2, h2b, 1);

  // ---- Layer 3: feat3 + projected residual GEMM, then agg, then FC ----
  k_gemm_mfma<4,2,1><<<gemm_blocks, 256, 0, stream>>>(h2b, Bf3, featb, res3p, al3, ar3, el, er, NN);
  k_agg1<<<NN/4, 256, 0, stream>>>(rowptr, csr, featb, el, er, res3p, b3, h3);
  k_fc<<<gemm_blocks, 256, 0, stream>>>(h3, Wfc, bfc, out);
}

// Round 9
// 294.156 us; speedup vs baseline: 1.5682x; 1.0925x over previous
//
#include <hip/hip_runtime.h>
#include <cstdint>
#include <cstddef>

#define NN 100000
#define NE 1000000
#define GEMM_BLOCKS 1563           // (NN+63)/64
#define TICKET_BLOCKS 3907         // (NE+255)/256
#define CAST_BLOCKS 12500          // NN*128/4 / 256
#define LOG2E 1.4426950408896340736f

typedef unsigned int uint;
typedef unsigned short ushort;
typedef __attribute__((ext_vector_type(8))) short bfrag;   // 8 bf16 = 4 VGPR
typedef __attribute__((ext_vector_type(4))) float f32x4;

__device__ __forceinline__ ushort f2bf(float f){
  uint u = __float_as_uint(f);
  u += 0x7fffu + ((u >> 16) & 1u);     // round-to-nearest-even
  return (ushort)(u >> 16);
}
__device__ __forceinline__ float bflo(uint p){ return __uint_as_float(p << 16); }
__device__ __forceinline__ float bfhi(uint p){ return __uint_as_float(p & 0xffff0000u); }

// ---------------- scans ----------------

__global__ __launch_bounds__(256) void k_scan_local(const int* __restrict__ cnt, int* __restrict__ rowptr,
                                                    int* __restrict__ bsum){
  __shared__ int sm[256];
  int t = threadIdx.x;
  int i = blockIdx.x*256 + t;
  int v = (i < NN) ? cnt[i] : 0;
  sm[t] = v;
  __syncthreads();
  for (int off=1; off<256; off<<=1){
    int u = (t>=off) ? sm[t-off] : 0;
    __syncthreads();
    sm[t] += u;
    __syncthreads();
  }
  if (i < NN) rowptr[i] = sm[t] - v;
  if (t == 255) bsum[blockIdx.x] = sm[255];
}

__global__ __launch_bounds__(512) void k_scan_bsum(const int* __restrict__ bsum, int* __restrict__ boff, int nb){
  __shared__ int sm[512];
  int t = threadIdx.x;
  int v = (t < nb) ? bsum[t] : 0;
  sm[t] = v;
  __syncthreads();
  for (int off=1; off<512; off<<=1){
    int u = (t>=off) ? sm[t-off] : 0;
    __syncthreads();
    sm[t] += u;
    __syncthreads();
  }
  if (t < nb) boff[t] = sm[t] - v;
}

__global__ __launch_bounds__(256) void k_scan_add(int* __restrict__ rowptr, const int* __restrict__ boff){
  int i = blockIdx.x*256 + threadIdx.x;
  if (i < NN) rowptr[i] += boff[i>>8];
  else if (i == NN) rowptr[NN] = NE;
}

// ---------------- fused prep: x cast + weight packs + CSR ticket pass ----------------

__device__ __forceinline__ void bfrag_body(const float* __restrict__ B1, const float* __restrict__ B2,
                                           int n1, int n2, int NT, ushort* __restrict__ out, int i){
  if (i >= NT*4*64) return;
  int l = i & 63, ks = (i>>6)&3, nt = i>>8;
  int col = nt*16 + (l&15);
  int k0  = ks*32 + (l>>4)*8;
  const float* B; int stride, c;
  if (col < n1){ B = B1; stride = n1; c = col; }
  else         { B = B2; stride = n2; c = col - n1; }
  ushort v[8];
  #pragma unroll
  for (int j=0;j<8;j++) v[j] = f2bf(B[(size_t)(k0+j)*stride + c]);
  uint4 pk;
  pk.x = (uint)v[0] | ((uint)v[1]<<16);
  pk.y = (uint)v[2] | ((uint)v[3]<<16);
  pk.z = (uint)v[4] | ((uint)v[5]<<16);
  pk.w = (uint)v[6] | ((uint)v[7]<<16);
  *(uint4*)(out + (size_t)i*8) = pk;
}

__global__ __launch_bounds__(256) void k_prep(const float* __restrict__ x, ushort* __restrict__ xb,
                                              const float* __restrict__ W1, const float* __restrict__ W2,
                                              const float* __restrict__ W3, const float* __restrict__ res3,
                                              ushort* __restrict__ Bf1, ushort* __restrict__ Bf2,
                                              ushort* __restrict__ Bf3,
                                              const int* __restrict__ dst, int* __restrict__ cnt,
                                              int* __restrict__ tick){
  int bid = blockIdx.x, t = threadIdx.x;
  if (bid < CAST_BLOCKS){
    int i = bid*256 + t;
    float4 v = ((const float4*)x)[i];
    uint2 p;
    p.x = (uint)f2bf(v.x) | ((uint)f2bf(v.y)<<16);
    p.y = (uint)f2bf(v.z) | ((uint)f2bf(v.w)<<16);
    ((uint2*)xb)[i] = p;
  } else if (bid < CAST_BLOCKS + 20){
    int r = bid - CAST_BLOCKS;
    if (r < 8)       bfrag_body(W1, nullptr, 128, 0, 8, Bf1, r*256 + t);
    else if (r < 16) bfrag_body(W2, nullptr, 128, 0, 8, Bf2, (r-8)*256 + t);
    else             bfrag_body(W3, res3,    32, 32, 4, Bf3, (r-16)*256 + t);
  } else {
    int e = (bid - CAST_BLOCKS - 20)*256 + t;
    if (e < NE) tick[e] = atomicAdd(&cnt[dst[e]], 1);
  }
}

// ---------------- MFMA GEMM body, K=128, no LDS ----------------
// el/er written PRE-SCALED by log2(e) (consumers use exp2).

template<int NT, int NTF, int H>
__device__ __forceinline__ void gemm_body(int bid, const ushort* __restrict__ Ab, const ushort* __restrict__ Bf,
                                          ushort* __restrict__ featb, float* __restrict__ Cres,
                                          const float* __restrict__ al, const float* __restrict__ ar,
                                          float* __restrict__ el, float* __restrict__ er, int M){
  int t = threadIdx.x;
  int l = t & 63, w = t >> 6;
  int rw = bid*64 + w*16;
  int c = l & 15, g = l >> 4;

  f32x4 acc[NT];
  #pragma unroll
  for (int nt=0;nt<NT;nt++) acc[nt] = (f32x4){0.f,0.f,0.f,0.f};

  int rowA = rw + c; if (rowA >= M) rowA = M-1;
  const ushort* Ap = Ab + (size_t)rowA*128 + g*8;
  const bfrag* Bp = (const bfrag*)Bf;

  #pragma unroll
  for (int ks=0; ks<4; ++ks){
    bfrag a = *(const bfrag*)(Ap + ks*32);
    #pragma unroll
    for (int nt=0; nt<NT; ++nt){
      bfrag b = Bp[(nt*4+ks)*64 + l];
      acc[nt] = __builtin_amdgcn_mfma_f32_16x16x32_bf16(a, b, acc[nt], 0, 0, 0);
    }
  }

  float alv[H][2], arv[H][2];
  #pragma unroll
  for (int h=0;h<H;h++){
    alv[h][0]=al[h*32+c]*LOG2E;    arv[h][0]=ar[h*32+c]*LOG2E;
    alv[h][1]=al[h*32+16+c]*LOG2E; arv[h][1]=ar[h*32+16+c]*LOG2E;
  }

  #pragma unroll
  for (int reg=0; reg<4; ++reg){
    int row = rw + g*4 + reg;
    bool ok = row < M;
    #pragma unroll
    for (int h=0;h<H;h++){
      float pl = acc[2*h][reg]*alv[h][0] + acc[2*h+1][reg]*alv[h][1];
      float pr = acc[2*h][reg]*arv[h][0] + acc[2*h+1][reg]*arv[h][1];
      #pragma unroll
      for (int off=1; off<16; off<<=1){ pl += __shfl_xor(pl,off); pr += __shfl_xor(pr,off); }
      if (ok && c==0){ el[(size_t)row*H + h] = pl; er[(size_t)row*H + h] = pr; }
    }
    if (ok){
      #pragma unroll
      for (int nt=0; nt<NTF; ++nt)
        featb[(size_t)row*(NTF*16) + nt*16 + c] = f2bf(acc[nt][reg]);
      #pragma unroll
      for (int nt=NTF; nt<NT; ++nt)
        Cres[(size_t)row*((NT-NTF)*16) + (nt-NTF)*16 + c] = acc[nt][reg];
    }
  }
}

template<int NT, int NTF, int H>
__global__ __launch_bounds__(256) void k_gemm_mfma(const ushort* __restrict__ Ab, const ushort* __restrict__ Bf,
                                                   ushort* __restrict__ featb, float* __restrict__ Cres,
                                                   const float* __restrict__ al, const float* __restrict__ ar,
                                                   float* __restrict__ el, float* __restrict__ er, int M){
  gemm_body<NT,NTF,H>(blockIdx.x, Ab, Bf, featb, Cres, al, ar, el, er, M);
}

// layer-1 GEMM fused with CSR placement (independent work, overlapped)
__global__ __launch_bounds__(256) void k_gemm1_place(const ushort* __restrict__ xb, const ushort* __restrict__ Bf1,
                                                     ushort* __restrict__ featb,
                                                     const float* __restrict__ al, const float* __restrict__ ar,
                                                     float* __restrict__ el, float* __restrict__ er,
                                                     const int* __restrict__ src, const int* __restrict__ dst,
                                                     const int* __restrict__ rowptr, const int* __restrict__ tick,
                                                     int* __restrict__ csr){
  int bid = blockIdx.x;
  if (bid < GEMM_BLOCKS){
    gemm_body<8,8,4>(bid, xb, Bf1, featb, nullptr, al, ar, el, er, NN);
  } else {
    int e = (bid - GEMM_BLOCKS)*256 + threadIdx.x;
    if (e < NE){
      int d = dst[e];
      csr[rowptr[d] + tick[e]] = src[e];
    }
  }
}

// ---------------- aggregation H=4: single-pass, quarter-lane layout ----------------
// 4 edges in flight (lane quarters); lane l15 owns feats 8*l15.. via one uint4 load.
// el/er pre-scaled by log2e -> v_exp_f32 directly. 32-bit gather offsets (saddr path).

template<int RK>
__global__ __launch_bounds__(256) void k_agg4(const int* __restrict__ rowptr, const int* __restrict__ csr,
                                              const ushort* __restrict__ feat,
                                              const float* __restrict__ el, const float* __restrict__ er,
                                              const void* __restrict__ res, const float* __restrict__ bias,
                                              ushort* __restrict__ out, int act){
  int lane = threadIdx.x & 63;
  int node = blockIdx.x*4 + (threadIdx.x >> 6);

  int beg = rowptr[node], deg = rowptr[node+1] - beg;
  int q = lane >> 4, l15 = lane & 15;
  int hm = l15 >> 2;
  float erh = er[(size_t)node*4 + hm];
  const int* cp = csr + beg;
  uint fo = (uint)l15*8u;

  float ssum = 0.f;
  float a0=0.f,a1=0.f,a2=0.f,a3=0.f,a4=0.f,a5=0.f,a6=0.f,a7=0.f;

  int ei = q;
  for (; ei + 4 < deg; ei += 8){
    int s0 = cp[ei], s1 = cp[ei+4];
    uint4 p0 = *(const uint4*)(feat + ((uint)s0*128u + fo));
    uint4 p1 = *(const uint4*)(feat + ((uint)s1*128u + fo));
    float v0 = el[(uint)s0*4u + hm] + erh; v0 = fmaxf(v0, 0.2f*v0);
    float v1 = el[(uint)s1*4u + hm] + erh; v1 = fmaxf(v1, 0.2f*v1);
    float w0 = __builtin_amdgcn_exp2f(v0);
    float w1 = __builtin_amdgcn_exp2f(v1);
    ssum += w0 + w1;
    a0 += w0*bflo(p0.x) + w1*bflo(p1.x);
    a1 += w0*bfhi(p0.x) + w1*bfhi(p1.x);
    a2 += w0*bflo(p0.y) + w1*bflo(p1.y);
    a3 += w0*bfhi(p0.y) + w1*bfhi(p1.y);
    a4 += w0*bflo(p0.z) + w1*bflo(p1.z);
    a5 += w0*bfhi(p0.z) + w1*bfhi(p1.z);
    a6 += w0*bflo(p0.w) + w1*bflo(p1.w);
    a7 += w0*bfhi(p0.w) + w1*bfhi(p1.w);
  }
  if (ei < deg){
    int s0 = cp[ei];
    uint4 p0 = *(const uint4*)(feat + ((uint)s0*128u + fo));
    float v0 = el[(uint)s0*4u + hm] + erh; v0 = fmaxf(v0, 0.2f*v0);
    float w0 = __builtin_amdgcn_exp2f(v0);
    ssum += w0;
    a0 += w0*bflo(p0.x); a1 += w0*bfhi(p0.x);
    a2 += w0*bflo(p0.y); a3 += w0*bfhi(p0.y);
    a4 += w0*bflo(p0.z); a5 += w0*bfhi(p0.z);
    a6 += w0*bflo(p0.w); a7 += w0*bfhi(p0.w);
  }

  // reduce across quarters (xor16, xor32 keep l15/hm)
  #pragma unroll
  for (int off=16; off<64; off<<=1){
    ssum += __shfl_xor(ssum, off);
    a0 += __shfl_xor(a0, off); a1 += __shfl_xor(a1, off);
    a2 += __shfl_xor(a2, off); a3 += __shfl_xor(a3, off);
    a4 += __shfl_xor(a4, off); a5 += __shfl_xor(a5, off);
    a6 += __shfl_xor(a6, off); a7 += __shfl_xor(a7, off);
  }
  float inv = (deg > 0) ? 1.f/ssum : 0.f;

  if (lane < 16){
    float o0=a0*inv, o1=a1*inv, o2=a2*inv, o3=a3*inv;
    float o4=a4*inv, o5=a5*inv, o6=a6*inv, o7=a7*inv;
    if (RK == 1){
      uint4 rv = *(const uint4*)((const ushort*)res + (size_t)node*128 + l15*8);
      o0 += bflo(rv.x); o1 += bfhi(rv.x); o2 += bflo(rv.y); o3 += bfhi(rv.y);
      o4 += bflo(rv.z); o5 += bfhi(rv.z); o6 += bflo(rv.w); o7 += bfhi(rv.w);
    }
    float4 bv0 = *(const float4*)(bias + l15*8);
    float4 bv1 = *(const float4*)(bias + l15*8 + 4);
    o0 += bv0.x; o1 += bv0.y; o2 += bv0.z; o3 += bv0.w;
    o4 += bv1.x; o5 += bv1.y; o6 += bv1.z; o7 += bv1.w;
    if (act){
      o0 = (o0>0.f)?o0:__expf(o0)-1.f;
      o1 = (o1>0.f)?o1:__expf(o1)-1.f;
      o2 = (o2>0.f)?o2:__expf(o2)-1.f;
      o3 = (o3>0.f)?o3:__expf(o3)-1.f;
      o4 = (o4>0.f)?o4:__expf(o4)-1.f;
      o5 = (o5>0.f)?o5:__expf(o5)-1.f;
      o6 = (o6>0.f)?o6:__expf(o6)-1.f;
      o7 = (o7>0.f)?o7:__expf(o7)-1.f;
    }
    uint4 pk;
    pk.x = (uint)f2bf(o0) | ((uint)f2bf(o1)<<16);
    pk.y = (uint)f2bf(o2) | ((uint)f2bf(o3)<<16);
    pk.z = (uint)f2bf(o4) | ((uint)f2bf(o5)<<16);
    pk.w = (uint)f2bf(o6) | ((uint)f2bf(o7)<<16);
    *(uint4*)(out + (size_t)node*128 + l15*8) = pk;
  }
}

// ---------------- aggregation H=1: single-pass, 8 substreams x 8 lanes ----------------

__global__ __launch_bounds__(256) void k_agg1(const int* __restrict__ rowptr, const int* __restrict__ csr,
                                              const ushort* __restrict__ feat,
                                              const float* __restrict__ el, const float* __restrict__ er,
                                              const float* __restrict__ res, const float* __restrict__ bias,
                                              float* __restrict__ h3){
  int lane = threadIdx.x & 63;
  int node = blockIdx.x*4 + (threadIdx.x >> 6);

  int beg = rowptr[node], deg = rowptr[node+1] - beg;
  int sub = lane >> 3, fl = lane & 7;
  float er0 = er[node];
  const int* cp = csr + beg;
  uint fo = (uint)fl*4u;

  float ssum = 0.f, a0=0.f, a1=0.f, a2=0.f, a3=0.f;
  for (int ei = sub; ei < deg; ei += 8){
    int s = cp[ei];
    uint2 pv = *(const uint2*)(feat + ((uint)s*32u + fo));
    float v = el[s] + er0; v = fmaxf(v, 0.2f*v);
    float w = __builtin_amdgcn_exp2f(v);
    ssum += w;
    a0 += w*bflo(pv.x); a1 += w*bfhi(pv.x);
    a2 += w*bflo(pv.y); a3 += w*bfhi(pv.y);
  }
  #pragma unroll
  for (int off=8; off<64; off<<=1){
    ssum += __shfl_xor(ssum, off);
    a0 += __shfl_xor(a0, off); a1 += __shfl_xor(a1, off);
    a2 += __shfl_xor(a2, off); a3 += __shfl_xor(a3, off);
  }
  float inv = (deg > 0) ? 1.f/ssum : 0.f;

  if (lane < 8){
    float4 rv = *(const float4*)(res + (size_t)node*32 + fl*4);
    float4 bv = *(const float4*)(bias + fl*4);
    float4 ov;
    ov.x = a0*inv + rv.x + bv.x;
    ov.y = a1*inv + rv.y + bv.y;
    ov.z = a2*inv + rv.z + bv.z;
    ov.w = a3*inv + rv.w + bv.w;
    *(float4*)(h3 + (size_t)node*32 + fl*4) = ov;
  }
}

// ---------------- final FC: out[N,40] = h[N,32] @ Wfc[32,40] + bfc ----------------

__global__ __launch_bounds__(256) void k_fc(const float* __restrict__ h, const float* __restrict__ W,
                                            const float* __restrict__ b, float* __restrict__ out){
  __shared__ float Ws[32*40];
  __shared__ float Hs[64][33];
  __shared__ float bs[40];
  int t = threadIdx.x;
  for (int i=t; i<1280; i+=256) Ws[i] = W[i];
  if (t < 40) bs[t] = b[t];
  int n0 = blockIdx.x*64;
  for (int idx=t; idx<512; idx+=256){
    int r = idx>>3, c4 = idx&7;
    float4 v;
    if (n0 + r < NN) v = *(const float4*)(h + (size_t)(n0+r)*32 + c4*4);
    else v = make_float4(0.f,0.f,0.f,0.f);
    Hs[r][c4*4+0]=v.x; Hs[r][c4*4+1]=v.y; Hs[r][c4*4+2]=v.z; Hs[r][c4*4+3]=v.w;
  }
  __syncthreads();
  int n = t>>2, cg = t&3;
  float acc[10];
  #pragma unroll
  for (int j=0;j<10;j++) acc[j] = 0.f;
  #pragma unroll
  for (int k=0;k<32;k++){
    float hv = Hs[n][k];
    #pragma unroll
    for (int j=0;j<10;j++) acc[j] += hv * Ws[k*40 + cg + 4*j];
  }
  int row = n0 + n;
  if (row < NN){
    #pragma unroll
    for (int j=0;j<10;j++) out[(size_t)row*40 + cg + 4*j] = acc[j] + bs[cg+4*j];
  }
}

// ---------------- launch ----------------

extern "C" void kernel_launch(void* const* d_in, const int* in_sizes, int n_in,
                              void* d_out, int out_size, void* d_ws, size_t ws_size,
                              hipStream_t stream){
  const float* x    = (const float*)d_in[0];
  const int*   src  = (const int*)  d_in[1];
  const int*   dst  = (const int*)  d_in[2];
  const float* W1   = (const float*)d_in[3];
  const float* al1  = (const float*)d_in[4];
  const float* ar1  = (const float*)d_in[5];
  const float* b1   = (const float*)d_in[6];
  const float* W2   = (const float*)d_in[7];
  const float* al2  = (const float*)d_in[8];
  const float* ar2  = (const float*)d_in[9];
  const float* b2   = (const float*)d_in[10];
  const float* W3   = (const float*)d_in[11];
  const float* al3  = (const float*)d_in[12];
  const float* ar3  = (const float*)d_in[13];
  const float* b3   = (const float*)d_in[14];
  const float* res3 = (const float*)d_in[15];
  const float* Wfc  = (const float*)d_in[16];
  const float* bfc  = (const float*)d_in[17];
  float* out = (float*)d_out;

  char* ws = (char*)d_ws;
  size_t o = 0;
  auto alloc = [&](size_t bytes)->char*{
    char* p = ws + o;
    o += (bytes + 255) & ~(size_t)255;
    return p;
  };
  int*    rowptr = (int*)   alloc((size_t)(NN+1)*4);
  int*    cnt    = (int*)   alloc((size_t)NN*4);
  int*    bsum   = (int*)   alloc(512*4);
  int*    boff   = (int*)   alloc(512*4);
  int*    tick   = (int*)   alloc((size_t)NE*4);
  int*    csr    = (int*)   alloc((size_t)NE*4);
  float*  el     = (float*) alloc((size_t)NN*4*4);
  float*  er     = (float*) alloc((size_t)NN*4*4);
  ushort* xb     = (ushort*)alloc((size_t)NN*128*2);
  ushort* featb  = (ushort*)alloc((size_t)NN*128*2);
  ushort* h1b    = (ushort*)alloc((size_t)NN*128*2);
  ushort* h2b    = (ushort*)alloc((size_t)NN*128*2);
  float*  res3p  = (float*) alloc((size_t)NN*32*4);
  float*  h3     = (float*) alloc((size_t)NN*32*4);
  ushort* Bf1    = (ushort*)alloc((size_t)8*4*64*8*2);
  ushort* Bf2    = (ushort*)alloc((size_t)8*4*64*8*2);
  ushort* Bf3    = (ushort*)alloc((size_t)4*4*64*8*2);
  (void)ws_size; (void)n_in; (void)in_sizes; (void)out_size;

  // prep (cast + weight packs) overlapped with CSR ticket pass
  hipMemsetAsync(cnt, 0, (size_t)NN*4, stream);
  k_prep<<<CAST_BLOCKS+20+TICKET_BLOCKS, 256, 0, stream>>>(x, xb, W1, W2, W3, res3,
                                                           Bf1, Bf2, Bf3, dst, cnt, tick);
  int nb = (NN+255)/256;
  k_scan_local<<<nb, 256, 0, stream>>>(cnt, rowptr, bsum);
  k_scan_bsum<<<1, 512, 0, stream>>>(bsum, boff, nb);
  k_scan_add<<<(NN+1+255)/256, 256, 0, stream>>>(rowptr, boff);

  // ---- Layer 1 GEMM overlapped with CSR placement ----
  k_gemm1_place<<<GEMM_BLOCKS+TICKET_BLOCKS, 256, 0, stream>>>(xb, Bf1, featb, al1, ar1, el, er,
                                                               src, dst, rowptr, tick, csr);
  k_agg4<0><<<NN/4, 256, 0, stream>>>(rowptr, csr, featb, el, er, nullptr, b1, h1b, 1);

  // ---- Layer 2 ----
  k_gemm_mfma<8,8,4><<<GEMM_BLOCKS, 256, 0, stream>>>(h1b, Bf2, featb, nullptr, al2, ar2, el, er, NN);
  k_agg4<1><<<NN/4, 256, 0, stream>>>(rowptr, csr, featb, el, er, h1b, b2, h2b, 1);

  // ---- Layer 3 ----
  k_gemm_mfma<4,2,1><<<GEMM_BLOCKS, 256, 0, stream>>>(h2b, Bf3, featb, res3p, al3, ar3, el, er, NN);
  k_agg1<<<NN/4, 256, 0, stream>>>(rowptr, csr, featb, el, er, res3p, b3, h3);
  k_fc<<<GEMM_BLOCKS, 256, 0, stream>>>(h3, Wfc, bfc, out);
}